// Round 1
// baseline (669.947 us; speedup 1.0000x reference)
//
#include <hip/hip_runtime.h>
#include <hip/hip_bf16.h>
#include <hip/hip_fp16.h>

#define BB 8
#define SS 4096
#define CC 640
#define CDIM 768
#define LTXT 77
#define NTOK 4
#define DH 80

typedef __attribute__((ext_vector_type(8))) _Float16 half8;
typedef __attribute__((ext_vector_type(4))) _Float16 half4;
typedef __attribute__((ext_vector_type(4))) float f32x4;

// ---------------------------------------------------------------- projections
// text K/V: (8,77,768)@(768,640); ip/ips K/V: (8,4,768)@(768,640)
__global__ __launch_bounds__(256, 2)
void proj_kernel(const float* __restrict__ ehs,
                 const float* __restrict__ Wk, const float* __restrict__ Wv,
                 const float* __restrict__ Wkip, const float* __restrict__ Wvip,
                 const float* __restrict__ Wksip,
                 float* __restrict__ ktxt, float* __restrict__ vtxt,
                 float* __restrict__ ipk, float* __restrict__ ipv,
                 float* __restrict__ ipsk)
{
    __shared__ float lrow[7][CDIM];
    const int job = blockIdx.x;
    const int tid = threadIdx.x;

    const float* W; float* outp; int b, l0src, outr0, nrows;
    if (job < 176) {                       // text: 2 weights x 8 b x 11 groups(7 rows)
        int wsel = job / 88; int rem = job % 88;
        b = rem / 11; int g = rem % 11;
        nrows = 7; l0src = g * 7; outr0 = b * LTXT + g * 7;
        W = wsel ? Wv : Wk; outp = wsel ? vtxt : ktxt;
    } else {                               // ip: 3 weights x 8 b, 4 rows
        int j2 = job - 176; int wsel = j2 >> 3; b = j2 & 7;
        nrows = 4; l0src = (wsel == 2) ? 81 : 77; outr0 = b * NTOK;
        W = (wsel == 0) ? Wkip : ((wsel == 1) ? Wvip : Wksip);
        outp = (wsel == 0) ? ipk : ((wsel == 1) ? ipv : ipsk);
    }
    // stage rows (clamped source so all 7 rows are valid reads)
    for (int idx = tid; idx < 7 * CDIM; idx += 256) {
        int rr = idx / CDIM, kk = idx % CDIM;
        int srow = l0src + rr; if (srow > 84) srow = 84;
        lrow[rr][kk] = ehs[(size_t)(b * 85 + srow) * CDIM + kk];
    }
    __syncthreads();
    for (int c = tid; c < CC; c += 256) {
        float acc[7];
        #pragma unroll
        for (int i = 0; i < 7; ++i) acc[i] = 0.f;
        for (int kk = 0; kk < CDIM; ++kk) {
            float wv = W[(size_t)kk * CC + c];
            #pragma unroll
            for (int rr = 0; rr < 7; ++rr) acc[rr] += lrow[rr][kk] * wv;
        }
        #pragma unroll
        for (int rr = 0; rr < 7; ++rr)
            if (rr < nrows) outp[(size_t)(outr0 + rr) * CC + c] = acc[rr];
    }
}

// ---------------------------------------------------------------- f16 MFMA GEMM
// C[M,640] = A[M,640] @ B[640,640]  (+ optional epilogue)
// EPI 0: store f16.  EPI 1: out = 0.5*(acc + bias[col]) + resid, store f32.
template<bool AHALF, int EPI>
__global__ __launch_bounds__(256)
void gemm640(const void* __restrict__ Ap, const float* __restrict__ Bp,
             const float* __restrict__ bias, const float* __restrict__ resid,
             void* __restrict__ Cp)
{
    __shared__ __align__(16) _Float16 sA[128][40];
    __shared__ __align__(16) _Float16 sB[128][40];   // transposed: [n][k]

    const int tid = threadIdx.x;
    const int lane = tid & 63;
    const int w = tid >> 6, wm = w >> 1, wn = w & 1;
    const int bmRow = blockIdx.x * 128;
    const int bnCol = blockIdx.y * 128;

    const int arow = tid >> 1, acol = (tid & 1) << 4;
    const int bk = tid >> 3, bcol = (tid & 7) << 4;

    f32x4 acc[4][4];
    #pragma unroll
    for (int m = 0; m < 4; ++m)
        #pragma unroll
        for (int n = 0; n < 4; ++n)
            acc[m][n] = (f32x4){0.f, 0.f, 0.f, 0.f};

    for (int k0 = 0; k0 < 640; k0 += 32) {
        if (AHALF) {
            const unsigned short* A = (const unsigned short*)Ap;
            const unsigned short* src = A + (size_t)(bmRow + arow) * 640 + k0 + acol;
            uint4 p0 = *(const uint4*)(src);
            uint4 p1 = *(const uint4*)(src + 8);
            *(uint4*)&sA[arow][acol] = p0;
            *(uint4*)&sA[arow][acol + 8] = p1;
        } else {
            const float* A = (const float*)Ap;
            const float* src = A + (size_t)(bmRow + arow) * 640 + k0 + acol;
            #pragma unroll
            for (int i0 = 0; i0 < 16; i0 += 4) {
                float4 f = *(const float4*)(src + i0);
                half4 hv = {(_Float16)f.x, (_Float16)f.y, (_Float16)f.z, (_Float16)f.w};
                *(half4*)&sA[arow][acol + i0] = hv;
            }
        }
        {
            const float* src = Bp + (size_t)(k0 + bk) * 640 + bnCol + bcol;
            #pragma unroll
            for (int i0 = 0; i0 < 16; i0 += 4) {
                float4 f = *(const float4*)(src + i0);
                sB[bcol + i0 + 0][bk] = (_Float16)f.x;
                sB[bcol + i0 + 1][bk] = (_Float16)f.y;
                sB[bcol + i0 + 2][bk] = (_Float16)f.z;
                sB[bcol + i0 + 3][bk] = (_Float16)f.w;
            }
        }
        __syncthreads();

        half8 af[4], bfr[4];
        #pragma unroll
        for (int m = 0; m < 4; ++m)
            af[m] = *(const half8*)&sA[wm * 64 + m * 16 + (lane & 15)][(lane >> 4) * 8];
        #pragma unroll
        for (int n = 0; n < 4; ++n)
            bfr[n] = *(const half8*)&sB[wn * 64 + n * 16 + (lane & 15)][(lane >> 4) * 8];
        #pragma unroll
        for (int m = 0; m < 4; ++m)
            #pragma unroll
            for (int n = 0; n < 4; ++n)
                acc[m][n] = __builtin_amdgcn_mfma_f32_16x16x32_f16(af[m], bfr[n], acc[m][n], 0, 0, 0);
        __syncthreads();
    }

    #pragma unroll
    for (int m = 0; m < 4; ++m) {
        #pragma unroll
        for (int n = 0; n < 4; ++n) {
            #pragma unroll
            for (int r = 0; r < 4; ++r) {
                int row = bmRow + wm * 64 + m * 16 + ((lane >> 4) << 2) + r;
                int col = bnCol + wn * 64 + n * 16 + (lane & 15);
                float v = acc[m][n][r];
                if (EPI == 0) {
                    ((_Float16*)Cp)[(size_t)row * 640 + col] = (_Float16)v;
                } else {
                    float o = 0.5f * (v + bias[col]) + resid[(size_t)row * 640 + col];
                    ((float*)Cp)[(size_t)row * 640 + col] = o;
                }
            }
        }
    }
}

// ---------------------------------------------------------------- attention
// One block per (64-query tile, bh). f32 math, f16 q in / f16 out.
#define KSTR 84
__global__ __launch_bounds__(256, 2)
void attn_kernel(const _Float16* __restrict__ qh,
                 const float* __restrict__ ktxt, const float* __restrict__ vtxt,
                 const float* __restrict__ ipk, const float* __restrict__ ipv,
                 const float* __restrict__ ipsk, const int* __restrict__ mask,
                 _Float16* __restrict__ attnout)
{
    __shared__ __align__(16) float regA[141 * KSTR];  // kt[77] + qt[64]; vt aliases kt/qt
    __shared__ __align__(16) float sc[64 * KSTR];
    __shared__ __align__(16) float ipkL[NTOK * DH];
    __shared__ __align__(16) float ipvL[NTOK * DH];
    __shared__ __align__(16) float ipskL[NTOK * DH];
    __shared__ float sipL[64 * 4];
    __shared__ float sipsL[64 * 4];
    __shared__ float pcombL[64 * 4];

    const int tile = blockIdx.x;
    const int bh = blockIdx.y;
    const int b = bh >> 3, h = bh & 7;
    const int tid = threadIdx.x;
    const float scale = 0.1118033988749895f;   // 1/sqrt(80)

    float* kt = regA;
    float* qt = regA + LTXT * KSTR;
    float* vt = regA;

    for (int idx = tid; idx < LTXT * DH; idx += 256) {
        int j = idx / DH, dd = idx % DH;
        kt[j * KSTR + dd] = ktxt[(size_t)(b * LTXT + j) * CC + h * DH + dd];
    }
    for (int idx = tid; idx < 64 * DH; idx += 256) {
        int r = idx / DH, dd = idx % DH;
        qt[r * KSTR + dd] = (float)qh[(size_t)(b * SS + tile * 64 + r) * CC + h * DH + dd];
    }
    for (int idx = tid; idx < NTOK * DH; idx += 256) {
        int t = idx / DH, dd = idx % DH;
        ipkL[idx]  = ipk [(size_t)(b * NTOK + t) * CC + h * DH + dd];
        ipvL[idx]  = ipv [(size_t)(b * NTOK + t) * CC + h * DH + dd];
        ipskL[idx] = ipsk[(size_t)(b * NTOK + t) * CC + h * DH + dd];
    }
    __syncthreads();

    const int r = tid >> 2, part = tid & 3;

    // phase 1: text scores + ip logits (needs kt, qt)
    {
        const int j0 = part * 20;
        const int cnt = (part == 3) ? 17 : 20;
        float accs[20];
        #pragma unroll
        for (int i = 0; i < 20; ++i) accs[i] = 0.f;
        for (int dd0 = 0; dd0 < DH; dd0 += 16) {
            float4 q0 = *(const float4*)&qt[r * KSTR + dd0];
            float4 q1 = *(const float4*)&qt[r * KSTR + dd0 + 4];
            float4 q2 = *(const float4*)&qt[r * KSTR + dd0 + 8];
            float4 q3 = *(const float4*)&qt[r * KSTR + dd0 + 12];
            #pragma unroll
            for (int jj = 0; jj < 20; ++jj) {
                if (jj < cnt) {
                    const float4* kp = (const float4*)&kt[(j0 + jj) * KSTR + dd0];
                    float4 k0 = kp[0], k1 = kp[1], k2 = kp[2], k3 = kp[3];
                    float s0 = q0.x*k0.x + q0.y*k0.y + q0.z*k0.z + q0.w*k0.w
                             + q1.x*k1.x + q1.y*k1.y + q1.z*k1.z + q1.w*k1.w
                             + q2.x*k2.x + q2.y*k2.y + q2.z*k2.z + q2.w*k2.w
                             + q3.x*k3.x + q3.y*k3.y + q3.z*k3.z + q3.w*k3.w;
                    accs[jj] += s0;
                }
            }
        }
        #pragma unroll
        for (int jj = 0; jj < 20; ++jj)
            if (jj < cnt) sc[r * KSTR + j0 + jj] = accs[jj] * scale;

        float aip = 0.f, aips = 0.f;
        for (int dd = 0; dd < DH; ++dd) {
            float qv = qt[r * KSTR + dd];
            aip  += qv * ipkL[part * DH + dd];
            aips += qv * ipskL[part * DH + dd];
        }
        sipL[r * 4 + part]  = aip * scale;
        sipsL[r * 4 + part] = aips * scale;
    }
    __syncthreads();

    // phase 1.5: stage V over kt/qt region (no reader of kt/qt remains)
    for (int idx = tid; idx < LTXT * DH; idx += 256) {
        int j = idx / DH, dd = idx % DH;
        vt[j * KSTR + dd] = vtxt[(size_t)(b * LTXT + j) * CC + h * DH + dd];
    }

    // phase 2: softmax (4 lanes per row) + ip combine
    {
        float mx = -1e30f;
        for (int j = part; j < LTXT; j += 4) mx = fmaxf(mx, sc[r * KSTR + j]);
        mx = fmaxf(mx, __shfl_xor(mx, 1));
        mx = fmaxf(mx, __shfl_xor(mx, 2));
        float sum = 0.f;
        for (int j = part; j < LTXT; j += 4) {
            float e = __expf(sc[r * KSTR + j] - mx);
            sc[r * KSTR + j] = e;
            sum += e;
        }
        sum += __shfl_xor(sum, 1);
        sum += __shfl_xor(sum, 2);
        float inv = 1.f / sum;
        for (int j = part; j < LTXT; j += 4) sc[r * KSTR + j] *= inv;

        float a = sipL[r * 4 + part];
        float ma = fmaxf(a, __shfl_xor(a, 1)); ma = fmaxf(ma, __shfl_xor(ma, 2));
        float ea = __expf(a - ma);
        float sa = ea; sa += __shfl_xor(sa, 1); sa += __shfl_xor(sa, 2);
        float pa = ea / sa;

        float bq = sipsL[r * 4 + part];
        float mb = fmaxf(bq, __shfl_xor(bq, 1)); mb = fmaxf(mb, __shfl_xor(mb, 2));
        float eb = __expf(bq - mb);
        float sb = eb; sb += __shfl_xor(sb, 1); sb += __shfl_xor(sb, 2);
        float pb = eb / sb;

        int gq = tile * 64 + r;
        float factor = (mask[gq] != 0) ? 0.01f : 1.0f;
        pcombL[r * 4 + part] = factor * fmaxf(pa, pb);
    }
    __syncthreads();

    // phase 3: out = P @ V + Pcomb @ ipV
    {
        const int dd0 = part * 20;
        float4 facc[5];
        #pragma unroll
        for (int i = 0; i < 5; ++i) facc[i] = (float4){0.f, 0.f, 0.f, 0.f};
        for (int j = 0; j < LTXT; ++j) {
            float p = sc[r * KSTR + j];
            const float4* vp = (const float4*)&vt[j * KSTR + dd0];
            #pragma unroll
            for (int i = 0; i < 5; ++i) {
                float4 v = vp[i];
                facc[i].x += p * v.x; facc[i].y += p * v.y;
                facc[i].z += p * v.z; facc[i].w += p * v.w;
            }
        }
        #pragma unroll
        for (int t = 0; t < 4; ++t) {
            float p = pcombL[r * 4 + t];
            const float4* vp = (const float4*)&ipvL[t * DH + dd0];
            #pragma unroll
            for (int i = 0; i < 5; ++i) {
                float4 v = vp[i];
                facc[i].x += p * v.x; facc[i].y += p * v.y;
                facc[i].z += p * v.z; facc[i].w += p * v.w;
            }
        }
        _Float16* dst = attnout + (size_t)(b * SS + tile * 64 + r) * CC + h * DH + dd0;
        #pragma unroll
        for (int i = 0; i < 5; ++i) {
            dst[i * 4 + 0] = (_Float16)facc[i].x;
            dst[i * 4 + 1] = (_Float16)facc[i].y;
            dst[i * 4 + 2] = (_Float16)facc[i].z;
            dst[i * 4 + 3] = (_Float16)facc[i].w;
        }
    }
}

// ---------------------------------------------------------------- launch
extern "C" void kernel_launch(void* const* d_in, const int* in_sizes, int n_in,
                              void* d_out, int out_size, void* d_ws, size_t ws_size,
                              hipStream_t stream) {
    const float* hidden = (const float*)d_in[0];
    const float* ehs    = (const float*)d_in[1];
    const int*   mask   = (const int*)d_in[2];
    const float* Wq     = (const float*)d_in[3];
    const float* Wk     = (const float*)d_in[4];
    const float* Wv     = (const float*)d_in[5];
    const float* Wkip   = (const float*)d_in[6];
    const float* Wvip   = (const float*)d_in[7];
    const float* Wksip  = (const float*)d_in[8];
    const float* Wo     = (const float*)d_in[9];
    const float* bo     = (const float*)d_in[10];

    char* ws = (char*)d_ws;
    _Float16* qh   = (_Float16*)(ws);                    // 41,943,040 B
    _Float16* attn = (_Float16*)(ws + 41943040);         // 41,943,040 B
    float* ktxt = (float*)(ws + 83886080);               // 1,576,960 B
    float* vtxt = (float*)(ws + 85463040);               // 1,576,960 B
    float* ipk  = (float*)(ws + 87040000);               // 81,920 B
    float* ipv  = (float*)(ws + 87121920);               // 81,920 B
    float* ipsk = (float*)(ws + 87203840);               // 81,920 B

    proj_kernel<<<200, 256, 0, stream>>>(ehs, Wk, Wv, Wkip, Wvip, Wksip,
                                         ktxt, vtxt, ipk, ipv, ipsk);
    gemm640<false, 0><<<dim3(256, 5), dim3(256), 0, stream>>>(hidden, Wq, nullptr, nullptr, qh);
    attn_kernel<<<dim3(64, 64), dim3(256), 0, stream>>>(qh, ktxt, vtxt, ipk, ipv, ipsk, mask, attn);
    gemm640<true, 1><<<dim3(256, 5), dim3(256), 0, stream>>>(attn, Wo, bo, hidden, (float*)d_out);
}

// Round 2
// 405.276 us; speedup vs baseline: 1.6531x; 1.6531x over previous
//
#include <hip/hip_runtime.h>
#include <hip/hip_bf16.h>
#include <hip/hip_fp16.h>

#define BB 8
#define SS 4096
#define CC 640
#define CDIM 768
#define LTXT 77
#define NTOK 4
#define DH 80
#define ASTR 104   // padded LDS row stride (f16) for attention tiles

typedef __attribute__((ext_vector_type(8))) _Float16 half8;
typedef __attribute__((ext_vector_type(4))) float f32x4;

__device__ inline void gload_lds16(const void* g, void* l) {
    __builtin_amdgcn_global_load_lds((__attribute__((address_space(1))) void*)g,
                                     (__attribute__((address_space(3))) void*)l, 16, 0, 0);
}

// ---------------------------------------------------------------- converts
// flat f32 -> f16 (8 elems/thread)
__global__ __launch_bounds__(256)
void convert_a(const float* __restrict__ in, _Float16* __restrict__ out, int n8) {
    int i = blockIdx.x * 256 + threadIdx.x;
    if (i < n8) {
        const float4* p = (const float4*)(in + (size_t)i * 8);
        float4 a = p[0], b = p[1];
        half8 h = {(_Float16)a.x, (_Float16)a.y, (_Float16)a.z, (_Float16)a.w,
                   (_Float16)b.x, (_Float16)b.y, (_Float16)b.z, (_Float16)b.w};
        *(half8*)(out + (size_t)i * 8) = h;
    }
}

// W[640][640] f32 -> BT[n][k] f16 (transposed)
__global__ __launch_bounds__(256)
void convert_bt(const float* __restrict__ W, _Float16* __restrict__ BT) {
    __shared__ float t[64][65];
    int n0 = blockIdx.x * 64, k0 = blockIdx.y * 64;
    for (int idx = threadIdx.x; idx < 64 * 64; idx += 256) {
        int kk = idx >> 6, nn = idx & 63;
        t[kk][nn] = W[(size_t)(k0 + kk) * 640 + n0 + nn];
    }
    __syncthreads();
    for (int idx = threadIdx.x; idx < 64 * 64; idx += 256) {
        int nn = idx >> 6, kk = idx & 63;
        BT[(size_t)(n0 + nn) * 640 + k0 + kk] = (_Float16)t[kk][nn];
    }
}

// ---------------------------------------------------------------- projections (f16 out)
__global__ __launch_bounds__(256, 2)
void proj_kernel(const float* __restrict__ ehs,
                 const float* __restrict__ Wk, const float* __restrict__ Wv,
                 const float* __restrict__ Wkip, const float* __restrict__ Wvip,
                 const float* __restrict__ Wksip,
                 _Float16* __restrict__ ktxt, _Float16* __restrict__ vtxt,
                 _Float16* __restrict__ ipk, _Float16* __restrict__ ipv,
                 _Float16* __restrict__ ipsk)
{
    __shared__ float lrow[7][CDIM];
    const int job = blockIdx.x;
    const int tid = threadIdx.x;

    const float* W; _Float16* outp; int b, l0src, outr0, nrows;
    if (job < 176) {                       // text: 2 weights x 8 b x 11 groups(7 rows)
        int wsel = job / 88; int rem = job % 88;
        b = rem / 11; int g = rem % 11;
        nrows = 7; l0src = g * 7; outr0 = b * LTXT + g * 7;
        W = wsel ? Wv : Wk; outp = wsel ? vtxt : ktxt;
    } else {                               // ip: 3 weights x 8 b, 4 rows
        int j2 = job - 176; int wsel = j2 >> 3; b = j2 & 7;
        nrows = 4; l0src = (wsel == 2) ? 81 : 77; outr0 = b * NTOK;
        W = (wsel == 0) ? Wkip : ((wsel == 1) ? Wvip : Wksip);
        outp = (wsel == 0) ? ipk : ((wsel == 1) ? ipv : ipsk);
    }
    for (int idx = tid; idx < 7 * CDIM; idx += 256) {
        int rr = idx / CDIM, kk = idx % CDIM;
        int srow = l0src + rr; if (srow > 84) srow = 84;
        lrow[rr][kk] = ehs[(size_t)(b * 85 + srow) * CDIM + kk];
    }
    __syncthreads();
    for (int c = tid; c < CC; c += 256) {
        float acc[7];
        #pragma unroll
        for (int i = 0; i < 7; ++i) acc[i] = 0.f;
        for (int kk = 0; kk < CDIM; ++kk) {
            float wv = W[(size_t)kk * CC + c];
            #pragma unroll
            for (int rr = 0; rr < 7; ++rr) acc[rr] += lrow[rr][kk] * wv;
        }
        #pragma unroll
        for (int rr = 0; rr < 7; ++rr)
            if (rr < nrows) outp[(size_t)(outr0 + rr) * CC + c] = (_Float16)acc[rr];
    }
}

// ---------------------------------------------------------------- f16 MFMA GEMM (BK=64, swizzled gload_lds)
// C[M,640] = A[M,640] @ BT[640,640]^T.  EPI 0: f16 store. EPI 1: 0.5*(acc+bias)+resid, f32.
template<int EPI>
__global__ __launch_bounds__(256)
void gemm_f16(const _Float16* __restrict__ A, const _Float16* __restrict__ BT,
              const float* __restrict__ bias, const float* __restrict__ resid,
              void* __restrict__ Cp)
{
    __shared__ __align__(16) _Float16 sA[128 * 64];
    __shared__ __align__(16) _Float16 sB[128 * 64];

    const int tid = threadIdx.x;
    const int lane = tid & 63;
    const int w = tid >> 6, wm = w >> 1, wn = w & 1;
    const int lrow = lane & 15, lhi = lane >> 4;
    const int bm = blockIdx.x * 128, bn = blockIdx.y * 128;

    f32x4 acc[4][4];
    #pragma unroll
    for (int mt = 0; mt < 4; ++mt)
        #pragma unroll
        for (int nt = 0; nt < 4; ++nt)
            acc[mt][nt] = (f32x4){0.f, 0.f, 0.f, 0.f};

    for (int k0 = 0; k0 < 640; k0 += 64) {
        #pragma unroll
        for (int p = 0; p < 4; ++p) {
            int s = p * 256 + tid;              // 16B slot 0..1023
            int row = s >> 3, sub = s & 7;
            int c = sub ^ (row & 7);            // inverse-swizzled source
            gload_lds16(A  + (size_t)(bm + row) * 640 + k0 + c * 8, sA + s * 8);
            gload_lds16(BT + (size_t)(bn + row) * 640 + k0 + c * 8, sB + s * 8);
        }
        __syncthreads();
        #pragma unroll
        for (int ks = 0; ks < 2; ++ks) {
            half8 af[4], bf[4];
            #pragma unroll
            for (int mt = 0; mt < 4; ++mt) {
                int row = wm * 64 + mt * 16 + lrow;
                int sub = (ks * 4 + lhi) ^ (row & 7);
                af[mt] = *(const half8*)&sA[row * 64 + sub * 8];
            }
            #pragma unroll
            for (int nt = 0; nt < 4; ++nt) {
                int row = wn * 64 + nt * 16 + lrow;
                int sub = (ks * 4 + lhi) ^ (row & 7);
                bf[nt] = *(const half8*)&sB[row * 64 + sub * 8];
            }
            #pragma unroll
            for (int mt = 0; mt < 4; ++mt)
                #pragma unroll
                for (int nt = 0; nt < 4; ++nt)
                    acc[mt][nt] = __builtin_amdgcn_mfma_f32_16x16x32_f16(af[mt], bf[nt], acc[mt][nt], 0, 0, 0);
        }
        __syncthreads();
    }

    #pragma unroll
    for (int mt = 0; mt < 4; ++mt) {
        #pragma unroll
        for (int nt = 0; nt < 4; ++nt) {
            int row0 = bm + wm * 64 + mt * 16 + lhi * 4;
            int col = bn + wn * 64 + nt * 16 + lrow;
            #pragma unroll
            for (int r = 0; r < 4; ++r) {
                float v = acc[mt][nt][r];
                if (EPI == 0) {
                    ((_Float16*)Cp)[(size_t)(row0 + r) * 640 + col] = (_Float16)v;
                } else {
                    float o = 0.5f * (v + bias[col]) + resid[(size_t)(row0 + r) * 640 + col];
                    ((float*)Cp)[(size_t)(row0 + r) * 640 + col] = o;
                }
            }
        }
    }
}

// ---------------------------------------------------------------- MFMA attention
// Block: 64 queries x one (b,h). 4 waves, 16 q-rows each.
// K-pack rows: 0..76 text, 77..79 zero, 80..83 ip, 84..87 ips, 88..95 zero.
__global__ __launch_bounds__(256, 2)
void attn_kernel(const _Float16* __restrict__ qh,
                 const _Float16* __restrict__ ktxt, const _Float16* __restrict__ vtxt,
                 const _Float16* __restrict__ ipk, const _Float16* __restrict__ ipv,
                 const _Float16* __restrict__ ipsk, const int* __restrict__ mask,
                 _Float16* __restrict__ attnout)
{
    __shared__ __align__(16) _Float16 sQ[64 * ASTR];
    __shared__ __align__(16) _Float16 sK[96 * ASTR];
    __shared__ __align__(16) _Float16 sVT[80 * ASTR];   // [d][j]: j 0..76 text V, 80..83 ipV
    __shared__ __align__(16) _Float16 sP[64 * ASTR];

    const int tile = blockIdx.x;
    const int bh = blockIdx.y;
    const int b = bh >> 3, h = bh & 7;
    const int tid = threadIdx.x;
    const float scale = 0.11180339887498948f;   // 1/sqrt(80)
    const half8 hz = {0, 0, 0, 0, 0, 0, 0, 0};

    // ---- phase 0: stage Q, K-pack; zero VT
    for (int idx = tid; idx < 64 * 13; idx += 256) {
        int row = idx / 13, c8 = idx % 13;
        half8 v = hz;
        if (c8 < 10) v = *(const half8*)&qh[(size_t)(b * SS + tile * 64 + row) * 640 + h * DH + c8 * 8];
        *(half8*)&sQ[row * ASTR + c8 * 8] = v;
    }
    for (int idx = tid; idx < 96 * 13; idx += 256) {
        int row = idx / 13, c8 = idx % 13;
        half8 v = hz;
        if (c8 < 10) {
            if (row < 77)                       v = *(const half8*)&ktxt[(size_t)(b * LTXT + row) * 640 + h * DH + c8 * 8];
            else if (row >= 80 && row < 84)     v = *(const half8*)&ipk [(size_t)(b * NTOK + row - 80) * 640 + h * DH + c8 * 8];
            else if (row >= 84 && row < 88)     v = *(const half8*)&ipsk[(size_t)(b * NTOK + row - 84) * 640 + h * DH + c8 * 8];
        }
        *(half8*)&sK[row * ASTR + c8 * 8] = v;
    }
    for (int idx = tid; idx < 80 * 13; idx += 256)
        *(half8*)&sVT[(idx / 13) * ASTR + (idx % 13) * 8] = hz;
    __syncthreads();

    // ---- phase 0b: transposed V fill (coalesced global, scalar LDS writes)
    for (int idx = tid; idx < 77 * 10; idx += 256) {
        int j = idx / 10, c8 = idx % 10;
        half8 v = *(const half8*)&vtxt[(size_t)(b * LTXT + j) * 640 + h * DH + c8 * 8];
        #pragma unroll
        for (int e = 0; e < 8; ++e) sVT[(c8 * 8 + e) * ASTR + j] = v[e];
    }
    for (int idx = tid; idx < 4 * 10; idx += 256) {
        int j = idx / 10, c8 = idx % 10;
        half8 v = *(const half8*)&ipv[(size_t)(b * NTOK + j) * 640 + h * DH + c8 * 8];
        #pragma unroll
        for (int e = 0; e < 8; ++e) sVT[(c8 * 8 + e) * ASTR + (80 + j)] = v[e];
    }
    __syncthreads();

    // ---- per-wave compute
    const int lane = tid & 63;
    const int w = tid >> 6;
    const int rb = w * 16;
    const int lrow = lane & 15, lhi = lane >> 4;

    f32x4 acc[6];
    #pragma unroll
    for (int nt = 0; nt < 6; ++nt) acc[nt] = (f32x4){0.f, 0.f, 0.f, 0.f};

    {
        const _Float16* qbase = &sQ[(rb + lrow) * ASTR + lhi * 8];
        half8 a0 = *(const half8*)(qbase);
        half8 a1 = *(const half8*)(qbase + 32);
        half8 a2 = *(const half8*)(qbase + 64);
        #pragma unroll
        for (int nt = 0; nt < 6; ++nt) {
            const _Float16* kb = &sK[(nt * 16 + lrow) * ASTR + lhi * 8];
            acc[nt] = __builtin_amdgcn_mfma_f32_16x16x32_f16(a0, *(const half8*)(kb),      acc[nt], 0, 0, 0);
            acc[nt] = __builtin_amdgcn_mfma_f32_16x16x32_f16(a1, *(const half8*)(kb + 32), acc[nt], 0, 0, 0);
            acc[nt] = __builtin_amdgcn_mfma_f32_16x16x32_f16(a2, *(const half8*)(kb + 64), acc[nt], 0, 0, 0);
        }
    }

    #pragma unroll
    for (int nt = 0; nt < 6; ++nt) acc[nt] = acc[nt] * scale;

    const bool t4ok = (64 + lrow) < 77;
    #pragma unroll
    for (int r = 0; r < 4; ++r) {
        // text softmax over cols 0..76
        float v4 = t4ok ? acc[4][r] : -1e30f;
        float m = fmaxf(fmaxf(acc[0][r], acc[1][r]), fmaxf(acc[2][r], acc[3][r]));
        m = fmaxf(m, v4);
        m = fmaxf(m, __shfl_xor(m, 1));
        m = fmaxf(m, __shfl_xor(m, 2));
        m = fmaxf(m, __shfl_xor(m, 4));
        m = fmaxf(m, __shfl_xor(m, 8));
        float e0 = __expf(acc[0][r] - m), e1 = __expf(acc[1][r] - m);
        float e2 = __expf(acc[2][r] - m), e3 = __expf(acc[3][r] - m);
        float e4 = t4ok ? __expf(acc[4][r] - m) : 0.f;
        float sm = e0 + e1 + e2 + e3 + e4;
        sm += __shfl_xor(sm, 1); sm += __shfl_xor(sm, 2);
        sm += __shfl_xor(sm, 4); sm += __shfl_xor(sm, 8);
        float inv = 1.f / sm;
        acc[0][r] = e0 * inv; acc[1][r] = e1 * inv; acc[2][r] = e2 * inv;
        acc[3][r] = e3 * inv; acc[4][r] = e4 * inv;

        // ip/ips softmax: cols 80..83 (lanes 0..3) and 84..87 (lanes 4..7)
        float s5 = acc[5][r];
        float m5 = fmaxf(s5, __shfl_xor(s5, 1));
        m5 = fmaxf(m5, __shfl_xor(m5, 2));
        float e5 = __expf(s5 - m5);
        float sm5 = e5 + __shfl_xor(e5, 1);
        sm5 += __shfl_xor(sm5, 2);
        float p5 = e5 / sm5;
        float po = __shfl_xor(p5, 4);
        int gq = tile * 64 + rb + lhi * 4 + r;
        float fac = (mask[gq] != 0) ? 0.01f : 1.0f;
        float pc = fmaxf(p5, po) * fac;
        acc[5][r] = (lrow < 4) ? pc : 0.f;
    }

    // write P (wave-local rows)
    #pragma unroll
    for (int nt = 0; nt < 6; ++nt)
        #pragma unroll
        for (int r = 0; r < 4; ++r)
            sP[(rb + lhi * 4 + r) * ASTR + nt * 16 + lrow] = (_Float16)acc[nt][r];

    // PV (no barrier needed: wave reads only its own P rows; VT staged before barrier)
    f32x4 o[5];
    #pragma unroll
    for (int nt = 0; nt < 5; ++nt) o[nt] = (f32x4){0.f, 0.f, 0.f, 0.f};
    {
        const _Float16* pbase = &sP[(rb + lrow) * ASTR + lhi * 8];
        half8 a0 = *(const half8*)(pbase);
        half8 a1 = *(const half8*)(pbase + 32);
        half8 a2 = *(const half8*)(pbase + 64);
        #pragma unroll
        for (int nt = 0; nt < 5; ++nt) {
            const _Float16* vb = &sVT[(nt * 16 + lrow) * ASTR + lhi * 8];
            o[nt] = __builtin_amdgcn_mfma_f32_16x16x32_f16(a0, *(const half8*)(vb),      o[nt], 0, 0, 0);
            o[nt] = __builtin_amdgcn_mfma_f32_16x16x32_f16(a1, *(const half8*)(vb + 32), o[nt], 0, 0, 0);
            o[nt] = __builtin_amdgcn_mfma_f32_16x16x32_f16(a2, *(const half8*)(vb + 64), o[nt], 0, 0, 0);
        }
    }

    #pragma unroll
    for (int nt = 0; nt < 5; ++nt)
        #pragma unroll
        for (int r = 0; r < 4; ++r)
            attnout[(size_t)(b * SS + tile * 64 + rb + lhi * 4 + r) * 640 + h * DH + nt * 16 + lrow] =
                (_Float16)o[nt][r];
}

// ---------------------------------------------------------------- launch
extern "C" void kernel_launch(void* const* d_in, const int* in_sizes, int n_in,
                              void* d_out, int out_size, void* d_ws, size_t ws_size,
                              hipStream_t stream) {
    const float* hidden = (const float*)d_in[0];
    const float* ehs    = (const float*)d_in[1];
    const int*   mask   = (const int*)d_in[2];
    const float* Wq     = (const float*)d_in[3];
    const float* Wk     = (const float*)d_in[4];
    const float* Wv     = (const float*)d_in[5];
    const float* Wkip   = (const float*)d_in[6];
    const float* Wvip   = (const float*)d_in[7];
    const float* Wksip  = (const float*)d_in[8];
    const float* Wo     = (const float*)d_in[9];
    const float* bo     = (const float*)d_in[10];

    char* ws = (char*)d_ws;
    _Float16* AhAttn = (_Float16*)(ws);                    // hidden f16, later attnout (aliased)
    _Float16* qh     = (_Float16*)(ws + 41943040);
    _Float16* BqT    = (_Float16*)(ws + 83886080);
    _Float16* BoT    = (_Float16*)(ws + 84705280);
    _Float16* ktxt   = (_Float16*)(ws + 85524480);
    _Float16* vtxt   = (_Float16*)(ws + 86312960);
    _Float16* ipk    = (_Float16*)(ws + 87101440);
    _Float16* ipv    = (_Float16*)(ws + 87142400);
    _Float16* ipsk   = (_Float16*)(ws + 87183360);

    convert_bt<<<dim3(10, 10), 256, 0, stream>>>(Wq, BqT);
    convert_bt<<<dim3(10, 10), 256, 0, stream>>>(Wo, BoT);
    convert_a<<<10240, 256, 0, stream>>>(hidden, AhAttn, 2621440);
    proj_kernel<<<200, 256, 0, stream>>>(ehs, Wk, Wv, Wkip, Wvip, Wksip,
                                         ktxt, vtxt, ipk, ipv, ipsk);
    gemm_f16<0><<<dim3(256, 5), 256, 0, stream>>>(AhAttn, BqT, nullptr, nullptr, qh);
    attn_kernel<<<dim3(64, 64), 256, 0, stream>>>(qh, ktxt, vtxt, ipk, ipv, ipsk, mask, AhAttn);
    gemm_f16<1><<<dim3(256, 5), 256, 0, stream>>>(AhAttn, BoT, bo, hidden, d_out);
}

// Round 4
// 217.505 us; speedup vs baseline: 3.0801x; 1.8633x over previous
//
#include <hip/hip_runtime.h>
#include <hip/hip_bf16.h>
#include <hip/hip_fp16.h>

#define BB 8
#define SS 4096
#define CC 640
#define CDIM 768
#define LTXT 77
#define NTOK 4
#define DH 80
#define ASTR 104   // padded LDS row stride (f16) for attention tiles

typedef __attribute__((ext_vector_type(8))) _Float16 half8;
typedef __attribute__((ext_vector_type(4))) float f32x4;

__device__ inline void gload_lds16(const void* g, void* l) {
    __builtin_amdgcn_global_load_lds((__attribute__((address_space(1))) void*)g,
                                     (__attribute__((address_space(3))) void*)l, 16, 0, 0);
}

// ---------------------------------------------------------------- converts
// flat f32 -> f16 (8 elems/thread)
__global__ __launch_bounds__(256)
void convert_a(const float* __restrict__ in, _Float16* __restrict__ out, int n8) {
    int i = blockIdx.x * 256 + threadIdx.x;
    if (i < n8) {
        const float4* p = (const float4*)(in + (size_t)i * 8);
        float4 a = p[0], b = p[1];
        half8 h = {(_Float16)a.x, (_Float16)a.y, (_Float16)a.z, (_Float16)a.w,
                   (_Float16)b.x, (_Float16)b.y, (_Float16)b.z, (_Float16)b.w};
        *(half8*)(out + (size_t)i * 8) = h;
    }
}

// W[K][640] f32 -> T[n][k] f16 (transposed). z selects which of two weights.
__global__ __launch_bounds__(256)
void convert_bt2(const float* __restrict__ W0, const float* __restrict__ W1,
                 _Float16* __restrict__ T0, _Float16* __restrict__ T1, int K) {
    __shared__ float t[64][65];
    const float* W = blockIdx.z ? W1 : W0;
    _Float16* T = blockIdx.z ? T1 : T0;
    int n0 = blockIdx.x * 64, k0 = blockIdx.y * 64;
    for (int idx = threadIdx.x; idx < 64 * 64; idx += 256) {
        int kk = idx >> 6, nn = idx & 63;
        t[kk][nn] = W[(size_t)(k0 + kk) * 640 + n0 + nn];
    }
    __syncthreads();
    for (int idx = threadIdx.x; idx < 64 * 64; idx += 256) {
        int nn = idx >> 6, kk = idx & 63;
        T[(size_t)(n0 + nn) * K + k0 + kk] = (_Float16)t[kk][nn];
    }
}

// 5 projection weights [768][640] f32 -> [640][768] f16, z selects weight
__global__ __launch_bounds__(256)
void convert_bt5(const float* __restrict__ W0, const float* __restrict__ W1,
                 const float* __restrict__ W2, const float* __restrict__ W3,
                 const float* __restrict__ W4,
                 _Float16* __restrict__ T0, _Float16* __restrict__ T1,
                 _Float16* __restrict__ T2, _Float16* __restrict__ T3,
                 _Float16* __restrict__ T4) {
    __shared__ float t[64][65];
    int z = blockIdx.z;
    const float* W = (z == 0) ? W0 : (z == 1) ? W1 : (z == 2) ? W2 : (z == 3) ? W3 : W4;
    _Float16* T = (z == 0) ? T0 : (z == 1) ? T1 : (z == 2) ? T2 : (z == 3) ? T3 : T4;
    int n0 = blockIdx.x * 64, k0 = blockIdx.y * 64;
    for (int idx = threadIdx.x; idx < 64 * 64; idx += 256) {
        int kk = idx >> 6, nn = idx & 63;
        t[kk][nn] = W[(size_t)(k0 + kk) * 640 + n0 + nn];
    }
    __syncthreads();
    for (int idx = threadIdx.x; idx < 64 * 64; idx += 256) {
        int nn = idx >> 6, kk = idx & 63;
        T[(size_t)(n0 + nn) * CDIM + k0 + kk] = (_Float16)t[kk][nn];
    }
}

// ---------------------------------------------------------------- projection MFMA GEMM
// Virtual jobs: 0..199 text (wsel 0,1: Wk,Wv; M=616), 200..229 ip (wsel 2,3,4; M=32).
// 64x64 tile, K=768, 4 waves each 32x32.
__global__ __launch_bounds__(256)
void proj_gemm(const _Float16* __restrict__ A16,
               const _Float16* __restrict__ WT0, const _Float16* __restrict__ WT1,
               const _Float16* __restrict__ WT2, const _Float16* __restrict__ WT3,
               const _Float16* __restrict__ WT4,
               _Float16* __restrict__ O0, _Float16* __restrict__ O1,
               _Float16* __restrict__ O2, _Float16* __restrict__ O3,
               _Float16* __restrict__ O4)
{
    __shared__ __align__(16) _Float16 sA[64 * 64];
    __shared__ __align__(16) _Float16 sB[64 * 64];
    const int tid = threadIdx.x;
    const int job = blockIdx.x;
    int wsel, mtile, ntile;
    if (job < 200) { wsel = job / 100; mtile = (job % 100) / 10; ntile = job % 10; }
    else { int j = job - 200; wsel = 2 + j / 10; mtile = 0; ntile = j % 10; }
    const _Float16* WT = (wsel == 0) ? WT0 : (wsel == 1) ? WT1 : (wsel == 2) ? WT2 : (wsel == 3) ? WT3 : WT4;
    _Float16* Op = (wsel == 0) ? O0 : (wsel == 1) ? O1 : (wsel == 2) ? O2 : (wsel == 3) ? O3 : O4;
    const int Mv = (wsel < 2) ? 616 : 32;
    const int bm = mtile * 64, bn = ntile * 64;

    // hoisted staging sources (row fixed per slot across K-loop)
    const _Float16* asrc[2];
    const _Float16* bsrc[2];
    int sslot[2];
    #pragma unroll
    for (int p = 0; p < 2; ++p) {
        int s = p * 256 + tid;
        int row = s >> 3, sub = s & 7;
        int c = sub ^ (row & 7);
        int m = bm + row; if (m > Mv - 1) m = Mv - 1;
        int srcrow;
        if (wsel < 2) srcrow = (m / 77) * 85 + (m % 77);
        else { int b2 = m >> 2, t2 = m & 3; srcrow = b2 * 85 + ((wsel == 4) ? 81 : 77) + t2; }
        asrc[p] = A16 + (size_t)srcrow * CDIM + c * 8;
        bsrc[p] = WT + (size_t)(bn + row) * CDIM + c * 8;
        sslot[p] = s * 8;
    }

    const int lane = tid & 63, w = tid >> 6;
    const int wm = w >> 1, wn = w & 1;
    const int lrow = lane & 15, lhi = lane >> 4;

    f32x4 acc[2][2];
    #pragma unroll
    for (int mt = 0; mt < 2; ++mt)
        #pragma unroll
        for (int nt = 0; nt < 2; ++nt)
            acc[mt][nt] = (f32x4){0.f, 0.f, 0.f, 0.f};

    for (int k0 = 0; k0 < CDIM; k0 += 64) {
        #pragma unroll
        for (int p = 0; p < 2; ++p) {
            gload_lds16(asrc[p] + k0, sA + sslot[p]);
            gload_lds16(bsrc[p] + k0, sB + sslot[p]);
        }
        __syncthreads();
        #pragma unroll
        for (int ks = 0; ks < 2; ++ks) {
            half8 af[2], bf[2];
            #pragma unroll
            for (int mt = 0; mt < 2; ++mt) {
                int row = wm * 32 + mt * 16 + lrow;
                int sub = (ks * 4 + lhi) ^ (row & 7);
                af[mt] = *(const half8*)&sA[row * 64 + sub * 8];
            }
            #pragma unroll
            for (int nt = 0; nt < 2; ++nt) {
                int row = wn * 32 + nt * 16 + lrow;
                int sub = (ks * 4 + lhi) ^ (row & 7);
                bf[nt] = *(const half8*)&sB[row * 64 + sub * 8];
            }
            #pragma unroll
            for (int mt = 0; mt < 2; ++mt)
                #pragma unroll
                for (int nt = 0; nt < 2; ++nt)
                    acc[mt][nt] = __builtin_amdgcn_mfma_f32_16x16x32_f16(af[mt], bf[nt], acc[mt][nt], 0, 0, 0);
        }
        __syncthreads();
    }

    #pragma unroll
    for (int mt = 0; mt < 2; ++mt) {
        #pragma unroll
        for (int nt = 0; nt < 2; ++nt) {
            int col = bn + wn * 32 + nt * 16 + lrow;
            #pragma unroll
            for (int r = 0; r < 4; ++r) {
                int m = bm + wm * 32 + mt * 16 + lhi * 4 + r;
                if (m < Mv) Op[(size_t)m * 640 + col] = (_Float16)acc[mt][nt][r];
            }
        }
    }
}

// ---------------------------------------------------------------- f16 MFMA GEMM (BK=64, swizzled gload_lds)
// C[M,640] = A[M,640] @ BT[640,640]^T.  EPI 0: f16 store. EPI 1: 0.5*(acc+bias)+resid, f32.
template<int EPI>
__global__ __launch_bounds__(256)
void gemm_f16(const _Float16* __restrict__ A, const _Float16* __restrict__ BT,
              const float* __restrict__ bias, const float* __restrict__ resid,
              void* __restrict__ Cp)
{
    __shared__ __align__(16) _Float16 sA[128 * 64];
    __shared__ __align__(16) _Float16 sB[128 * 64];

    const int tid = threadIdx.x;
    const int lane = tid & 63;
    const int w = tid >> 6, wm = w >> 1, wn = w & 1;
    const int lrow = lane & 15, lhi = lane >> 4;
    const int bm = blockIdx.x * 128, bn = blockIdx.y * 128;

    f32x4 acc[4][4];
    #pragma unroll
    for (int mt = 0; mt < 4; ++mt)
        #pragma unroll
        for (int nt = 0; nt < 4; ++nt)
            acc[mt][nt] = (f32x4){0.f, 0.f, 0.f, 0.f};

    for (int k0 = 0; k0 < 640; k0 += 64) {
        #pragma unroll
        for (int p = 0; p < 4; ++p) {
            int s = p * 256 + tid;              // 16B slot 0..1023
            int row = s >> 3, sub = s & 7;
            int c = sub ^ (row & 7);            // inverse-swizzled source
            gload_lds16(A  + (size_t)(bm + row) * 640 + k0 + c * 8, sA + s * 8);
            gload_lds16(BT + (size_t)(bn + row) * 640 + k0 + c * 8, sB + s * 8);
        }
        __syncthreads();
        #pragma unroll
        for (int ks = 0; ks < 2; ++ks) {
            half8 af[4], bf[4];
            #pragma unroll
            for (int mt = 0; mt < 4; ++mt) {
                int row = wm * 64 + mt * 16 + lrow;
                int sub = (ks * 4 + lhi) ^ (row & 7);
                af[mt] = *(const half8*)&sA[row * 64 + sub * 8];
            }
            #pragma unroll
            for (int nt = 0; nt < 4; ++nt) {
                int row = wn * 64 + nt * 16 + lrow;
                int sub = (ks * 4 + lhi) ^ (row & 7);
                bf[nt] = *(const half8*)&sB[row * 64 + sub * 8];
            }
            #pragma unroll
            for (int mt = 0; mt < 4; ++mt)
                #pragma unroll
                for (int nt = 0; nt < 4; ++nt)
                    acc[mt][nt] = __builtin_amdgcn_mfma_f32_16x16x32_f16(af[mt], bf[nt], acc[mt][nt], 0, 0, 0);
        }
        __syncthreads();
    }

    #pragma unroll
    for (int mt = 0; mt < 4; ++mt) {
        #pragma unroll
        for (int nt = 0; nt < 4; ++nt) {
            int row0 = bm + wm * 64 + mt * 16 + lhi * 4;
            int col = bn + wn * 64 + nt * 16 + lrow;
            #pragma unroll
            for (int r = 0; r < 4; ++r) {
                float v = acc[mt][nt][r];
                if (EPI == 0) {
                    ((_Float16*)Cp)[(size_t)(row0 + r) * 640 + col] = (_Float16)v;
                } else {
                    float o = 0.5f * (v + bias[col]) + resid[(size_t)(row0 + r) * 640 + col];
                    ((float*)Cp)[(size_t)(row0 + r) * 640 + col] = o;
                }
            }
        }
    }
}

// ---------------------------------------------------------------- MFMA attention
// Block: 64 queries x one (b,h). 4 waves, 16 q-rows each.
// K-pack rows: 0..76 text, 77..79 zero, 80..83 ip, 84..87 ips, 88..95 zero.
// NOTE: attnout may alias qh (in-place): each block reads exactly the q-region
// it writes, all q reads complete before the block's first barrier, writes after.
__global__ __launch_bounds__(256, 2)
void attn_kernel(const _Float16* __restrict__ qh,
                 const _Float16* __restrict__ ktxt, const _Float16* __restrict__ vtxt,
                 const _Float16* __restrict__ ipk, const _Float16* __restrict__ ipv,
                 const _Float16* __restrict__ ipsk, const int* __restrict__ mask,
                 _Float16* __restrict__ attnout)
{
    __shared__ __align__(16) _Float16 sQ[64 * ASTR];
    __shared__ __align__(16) _Float16 sK[96 * ASTR];
    __shared__ __align__(16) _Float16 sVT[80 * ASTR];   // [d][j]: j 0..76 text V, 80..83 ipV
    __shared__ __align__(16) _Float16 sP[64 * ASTR];

    const int tile = blockIdx.x;
    const int bh = blockIdx.y;
    const int b = bh >> 3, h = bh & 7;
    const int tid = threadIdx.x;
    const float scale = 0.11180339887498948f;   // 1/sqrt(80)
    const half8 hz = {0, 0, 0, 0, 0, 0, 0, 0};

    // ---- phase 0: stage Q, K-pack; zero VT
    for (int idx = tid; idx < 64 * 13; idx += 256) {
        int row = idx / 13, c8 = idx % 13;
        half8 v = hz;
        if (c8 < 10) v = *(const half8*)&qh[(size_t)(b * SS + tile * 64 + row) * 640 + h * DH + c8 * 8];
        *(half8*)&sQ[row * ASTR + c8 * 8] = v;
    }
    for (int idx = tid; idx < 96 * 13; idx += 256) {
        int row = idx / 13, c8 = idx % 13;
        half8 v = hz;
        if (c8 < 10) {
            if (row < 77)                       v = *(const half8*)&ktxt[(size_t)(b * LTXT + row) * 640 + h * DH + c8 * 8];
            else if (row >= 80 && row < 84)     v = *(const half8*)&ipk [(size_t)(b * NTOK + row - 80) * 640 + h * DH + c8 * 8];
            else if (row >= 84 && row < 88)     v = *(const half8*)&ipsk[(size_t)(b * NTOK + row - 84) * 640 + h * DH + c8 * 8];
        }
        *(half8*)&sK[row * ASTR + c8 * 8] = v;
    }
    for (int idx = tid; idx < 80 * 13; idx += 256)
        *(half8*)&sVT[(idx / 13) * ASTR + (idx % 13) * 8] = hz;
    __syncthreads();

    // ---- phase 0b: transposed V fill (coalesced global, scalar LDS writes)
    for (int idx = tid; idx < 77 * 10; idx += 256) {
        int j = idx / 10, c8 = idx % 10;
        half8 v = *(const half8*)&vtxt[(size_t)(b * LTXT + j) * 640 + h * DH + c8 * 8];
        #pragma unroll
        for (int e = 0; e < 8; ++e) sVT[(c8 * 8 + e) * ASTR + j] = v[e];
    }
    for (int idx = tid; idx < 4 * 10; idx += 256) {
        int j = idx / 10, c8 = idx % 10;
        half8 v = *(const half8*)&ipv[(size_t)(b * NTOK + j) * 640 + h * DH + c8 * 8];
        #pragma unroll
        for (int e = 0; e < 8; ++e) sVT[(c8 * 8 + e) * ASTR + (80 + j)] = v[e];
    }
    __syncthreads();

    // ---- per-wave compute
    const int lane = tid & 63;
    const int w = tid >> 6;
    const int rb = w * 16;
    const int lrow = lane & 15, lhi = lane >> 4;

    f32x4 acc[6];
    #pragma unroll
    for (int nt = 0; nt < 6; ++nt) acc[nt] = (f32x4){0.f, 0.f, 0.f, 0.f};

    {
        const _Float16* qbase = &sQ[(rb + lrow) * ASTR + lhi * 8];
        half8 a0 = *(const half8*)(qbase);
        half8 a1 = *(const half8*)(qbase + 32);
        half8 a2 = *(const half8*)(qbase + 64);
        #pragma unroll
        for (int nt = 0; nt < 6; ++nt) {
            const _Float16* kb = &sK[(nt * 16 + lrow) * ASTR + lhi * 8];
            acc[nt] = __builtin_amdgcn_mfma_f32_16x16x32_f16(a0, *(const half8*)(kb),      acc[nt], 0, 0, 0);
            acc[nt] = __builtin_amdgcn_mfma_f32_16x16x32_f16(a1, *(const half8*)(kb + 32), acc[nt], 0, 0, 0);
            acc[nt] = __builtin_amdgcn_mfma_f32_16x16x32_f16(a2, *(const half8*)(kb + 64), acc[nt], 0, 0, 0);
        }
    }

    #pragma unroll
    for (int nt = 0; nt < 6; ++nt) acc[nt] = acc[nt] * scale;

    const bool t4ok = (64 + lrow) < 77;
    #pragma unroll
    for (int r = 0; r < 4; ++r) {
        // text softmax over cols 0..76
        float v4 = t4ok ? acc[4][r] : -1e30f;
        float m = fmaxf(fmaxf(acc[0][r], acc[1][r]), fmaxf(acc[2][r], acc[3][r]));
        m = fmaxf(m, v4);
        m = fmaxf(m, __shfl_xor(m, 1));
        m = fmaxf(m, __shfl_xor(m, 2));
        m = fmaxf(m, __shfl_xor(m, 4));
        m = fmaxf(m, __shfl_xor(m, 8));
        float e0 = __expf(acc[0][r] - m), e1 = __expf(acc[1][r] - m);
        float e2 = __expf(acc[2][r] - m), e3 = __expf(acc[3][r] - m);
        float e4 = t4ok ? __expf(acc[4][r] - m) : 0.f;
        float sm = e0 + e1 + e2 + e3 + e4;
        sm += __shfl_xor(sm, 1); sm += __shfl_xor(sm, 2);
        sm += __shfl_xor(sm, 4); sm += __shfl_xor(sm, 8);
        float inv = 1.f / sm;
        acc[0][r] = e0 * inv; acc[1][r] = e1 * inv; acc[2][r] = e2 * inv;
        acc[3][r] = e3 * inv; acc[4][r] = e4 * inv;

        // ip/ips softmax: cols 80..83 (lanes 0..3) and 84..87 (lanes 4..7)
        float s5 = acc[5][r];
        float m5 = fmaxf(s5, __shfl_xor(s5, 1));
        m5 = fmaxf(m5, __shfl_xor(m5, 2));
        float e5 = __expf(s5 - m5);
        float sm5 = e5 + __shfl_xor(e5, 1);
        sm5 += __shfl_xor(sm5, 2);
        float p5 = e5 / sm5;
        float po = __shfl_xor(p5, 4);
        int gq = tile * 64 + rb + lhi * 4 + r;
        float fac = (mask[gq] != 0) ? 0.01f : 1.0f;
        float pc = fmaxf(p5, po) * fac;
        acc[5][r] = (lrow < 4) ? pc : 0.f;
    }

    // write P (wave-local rows)
    #pragma unroll
    for (int nt = 0; nt < 6; ++nt)
        #pragma unroll
        for (int r = 0; r < 4; ++r)
            sP[(rb + lhi * 4 + r) * ASTR + nt * 16 + lrow] = (_Float16)acc[nt][r];

    // PV (no barrier needed: wave reads only its own P rows; VT staged before barrier)
    f32x4 o[5];
    #pragma unroll
    for (int nt = 0; nt < 5; ++nt) o[nt] = (f32x4){0.f, 0.f, 0.f, 0.f};
    {
        const _Float16* pbase = &sP[(rb + lrow) * ASTR + lhi * 8];
        half8 a0 = *(const half8*)(pbase);
        half8 a1 = *(const half8*)(pbase + 32);
        half8 a2 = *(const half8*)(pbase + 64);
        #pragma unroll
        for (int nt = 0; nt < 5; ++nt) {
            const _Float16* vb = &sVT[(nt * 16 + lrow) * ASTR + lhi * 8];
            o[nt] = __builtin_amdgcn_mfma_f32_16x16x32_f16(a0, *(const half8*)(vb),      o[nt], 0, 0, 0);
            o[nt] = __builtin_amdgcn_mfma_f32_16x16x32_f16(a1, *(const half8*)(vb + 32), o[nt], 0, 0, 0);
            o[nt] = __builtin_amdgcn_mfma_f32_16x16x32_f16(a2, *(const half8*)(vb + 64), o[nt], 0, 0, 0);
        }
    }

    #pragma unroll
    for (int nt = 0; nt < 5; ++nt)
        #pragma unroll
        for (int r = 0; r < 4; ++r)
            attnout[(size_t)(b * SS + tile * 64 + rb + lhi * 4 + r) * 640 + h * DH + nt * 16 + lrow] =
                (_Float16)o[nt][r];
}

// ---------------------------------------------------------------- launch
extern "C" void kernel_launch(void* const* d_in, const int* in_sizes, int n_in,
                              void* d_out, int out_size, void* d_ws, size_t ws_size,
                              hipStream_t stream) {
    const float* hidden = (const float*)d_in[0];
    const float* ehs    = (const float*)d_in[1];
    const int*   mask   = (const int*)d_in[2];
    const float* Wq     = (const float*)d_in[3];
    const float* Wk     = (const float*)d_in[4];
    const float* Wv     = (const float*)d_in[5];
    const float* Wkip   = (const float*)d_in[6];
    const float* Wvip   = (const float*)d_in[7];
    const float* Wksip  = (const float*)d_in[8];
    const float* Wo     = (const float*)d_in[9];
    const float* bo     = (const float*)d_in[10];

    // hidden-f16 (41,943,040 B) lives in d_out scratch: written by convert_a,
    // consumed by gemm1, dead before gemm2 overwrites d_out. d_out is 83.9 MB f32.
    _Float16* hid16 = (_Float16*)d_out;

    char* ws = (char*)d_ws;
    _Float16* qhA    = (_Float16*)(ws);                      // 41,943,040 B: q -> attn out (in-place)
    _Float16* BqT    = (_Float16*)(ws + 41943040);           // 819,200 B
    _Float16* BoT    = (_Float16*)(ws + 42762240);           // 819,200 B
    _Float16* ktxt   = (_Float16*)(ws + 43581440);           // 788,480 B
    _Float16* vtxt   = (_Float16*)(ws + 44369920);           // 788,480 B
    _Float16* ipk    = (_Float16*)(ws + 45158400);           // 40,960 B
    _Float16* ipv    = (_Float16*)(ws + 45199360);           // 40,960 B
    _Float16* ipsk   = (_Float16*)(ws + 45240320);           // 40,960 B
    _Float16* ehs16  = (_Float16*)(ws + 45281280);           // 1,044,480 B
    _Float16* WkT    = (_Float16*)(ws + 46325760);           // 983,040 B each
    _Float16* WvT    = (_Float16*)(ws + 47308800);
    _Float16* WkipT  = (_Float16*)(ws + 48291840);
    _Float16* WvipT  = (_Float16*)(ws + 49274880);
    _Float16* WksipT = (_Float16*)(ws + 50257920);           // ends 51,240,960 B

    convert_a<<<10240, 256, 0, stream>>>(hidden, hid16, 2621440);
    convert_a<<<255, 256, 0, stream>>>(ehs, ehs16, 65280);
    convert_bt2<<<dim3(10, 10, 2), 256, 0, stream>>>(Wq, Wo, BqT, BoT, 640);
    convert_bt5<<<dim3(10, 12, 5), 256, 0, stream>>>(Wk, Wv, Wkip, Wvip, Wksip,
                                                     WkT, WvT, WkipT, WvipT, WksipT);
    proj_gemm<<<230, 256, 0, stream>>>(ehs16, WkT, WvT, WkipT, WvipT, WksipT,
                                       ktxt, vtxt, ipk, ipv, ipsk);
    gemm_f16<0><<<dim3(256, 5), 256, 0, stream>>>(hid16, BqT, nullptr, nullptr, qhA);
    attn_kernel<<<dim3(64, 64), 256, 0, stream>>>(qhA, ktxt, vtxt, ipk, ipv, ipsk, mask, qhA);
    gemm_f16<1><<<dim3(256, 5), 256, 0, stream>>>(qhA, BoT, bo, hidden, d_out);
}

// Round 5
// 210.491 us; speedup vs baseline: 3.1828x; 1.0333x over previous
//
#include <hip/hip_runtime.h>
#include <hip/hip_bf16.h>
#include <hip/hip_fp16.h>

#define BB 8
#define SS 4096
#define CC 640
#define CDIM 768
#define LTXT 77
#define NTOK 4
#define DH 80
#define ASTR 104   // padded LDS row stride (f16) for attention tiles

typedef __attribute__((ext_vector_type(8))) _Float16 half8;
typedef __attribute__((ext_vector_type(4))) _Float16 half4;
typedef __attribute__((ext_vector_type(4))) float f32x4;

__device__ inline void gload_lds16(const void* g, void* l) {
    __builtin_amdgcn_global_load_lds((__attribute__((address_space(1))) void*)g,
                                     (__attribute__((address_space(3))) void*)l, 16, 0, 0);
}

// ---------------------------------------------------------------- converts
// flat f32 -> f16 (8 elems/thread)
__global__ __launch_bounds__(256)
void convert_a(const float* __restrict__ in, _Float16* __restrict__ out, int n8) {
    int i = blockIdx.x * 256 + threadIdx.x;
    if (i < n8) {
        const float4* p = (const float4*)(in + (size_t)i * 8);
        float4 a = p[0], b = p[1];
        half8 h = {(_Float16)a.x, (_Float16)a.y, (_Float16)a.z, (_Float16)a.w,
                   (_Float16)b.x, (_Float16)b.y, (_Float16)b.z, (_Float16)b.w};
        *(half8*)(out + (size_t)i * 8) = h;
    }
}

// W[K][640] f32 -> T[n][k] f16 (transposed). z selects which of two weights.
__global__ __launch_bounds__(256)
void convert_bt2(const float* __restrict__ W0, const float* __restrict__ W1,
                 _Float16* __restrict__ T0, _Float16* __restrict__ T1, int K) {
    __shared__ float t[64][65];
    const float* W = blockIdx.z ? W1 : W0;
    _Float16* T = blockIdx.z ? T1 : T0;
    int n0 = blockIdx.x * 64, k0 = blockIdx.y * 64;
    for (int idx = threadIdx.x; idx < 64 * 64; idx += 256) {
        int kk = idx >> 6, nn = idx & 63;
        t[kk][nn] = W[(size_t)(k0 + kk) * 640 + n0 + nn];
    }
    __syncthreads();
    for (int idx = threadIdx.x; idx < 64 * 64; idx += 256) {
        int nn = idx >> 6, kk = idx & 63;
        T[(size_t)(n0 + nn) * K + k0 + kk] = (_Float16)t[kk][nn];
    }
}

// 5 projection weights [768][640] f32 -> [640][768] f16, z selects weight
__global__ __launch_bounds__(256)
void convert_bt5(const float* __restrict__ W0, const float* __restrict__ W1,
                 const float* __restrict__ W2, const float* __restrict__ W3,
                 const float* __restrict__ W4,
                 _Float16* __restrict__ T0, _Float16* __restrict__ T1,
                 _Float16* __restrict__ T2, _Float16* __restrict__ T3,
                 _Float16* __restrict__ T4) {
    __shared__ float t[64][65];
    int z = blockIdx.z;
    const float* W = (z == 0) ? W0 : (z == 1) ? W1 : (z == 2) ? W2 : (z == 3) ? W3 : W4;
    _Float16* T = (z == 0) ? T0 : (z == 1) ? T1 : (z == 2) ? T2 : (z == 3) ? T3 : T4;
    int n0 = blockIdx.x * 64, k0 = blockIdx.y * 64;
    for (int idx = threadIdx.x; idx < 64 * 64; idx += 256) {
        int kk = idx >> 6, nn = idx & 63;
        t[kk][nn] = W[(size_t)(k0 + kk) * 640 + n0 + nn];
    }
    __syncthreads();
    for (int idx = threadIdx.x; idx < 64 * 64; idx += 256) {
        int nn = idx >> 6, kk = idx & 63;
        T[(size_t)(n0 + nn) * CDIM + k0 + kk] = (_Float16)t[kk][nn];
    }
}

// ---------------------------------------------------------------- projection MFMA GEMM
// Virtual jobs: 0..199 text (wsel 0,1: Wk,Wv; M=616), 200..229 ip (wsel 2,3,4; M=32).
// 64x64 tile, K=768, 4 waves each 32x32.
// wsel==1 (V) writes TRANSPOSED: vT[(b*640+col)*80 + j]  (j = m%77; slots 77..79 unwritten)
// wsel==3 (ipV) writes TRANSPOSED: ipvT[(b*640+col)*4 + t]
__global__ __launch_bounds__(256)
void proj_gemm(const _Float16* __restrict__ A16,
               const _Float16* __restrict__ WT0, const _Float16* __restrict__ WT1,
               const _Float16* __restrict__ WT2, const _Float16* __restrict__ WT3,
               const _Float16* __restrict__ WT4,
               _Float16* __restrict__ O0, _Float16* __restrict__ O1,
               _Float16* __restrict__ O2, _Float16* __restrict__ O3,
               _Float16* __restrict__ O4)
{
    __shared__ __align__(16) _Float16 sA[64 * 64];
    __shared__ __align__(16) _Float16 sB[64 * 64];
    const int tid = threadIdx.x;
    const int job = blockIdx.x;
    int wsel, mtile, ntile;
    if (job < 200) { wsel = job / 100; mtile = (job % 100) / 10; ntile = job % 10; }
    else { int j = job - 200; wsel = 2 + j / 10; mtile = 0; ntile = j % 10; }
    const _Float16* WT = (wsel == 0) ? WT0 : (wsel == 1) ? WT1 : (wsel == 2) ? WT2 : (wsel == 3) ? WT3 : WT4;
    const int Mv = (wsel < 2) ? 616 : 32;
    const int bm = mtile * 64, bn = ntile * 64;

    // hoisted staging sources (row fixed per slot across K-loop)
    const _Float16* asrc[2];
    const _Float16* bsrc[2];
    int sslot[2];
    #pragma unroll
    for (int p = 0; p < 2; ++p) {
        int s = p * 256 + tid;
        int row = s >> 3, sub = s & 7;
        int c = sub ^ (row & 7);
        int m = bm + row; if (m > Mv - 1) m = Mv - 1;
        int srcrow;
        if (wsel < 2) srcrow = (m / 77) * 85 + (m % 77);
        else { int b2 = m >> 2, t2 = m & 3; srcrow = b2 * 85 + ((wsel == 4) ? 81 : 77) + t2; }
        asrc[p] = A16 + (size_t)srcrow * CDIM + c * 8;
        bsrc[p] = WT + (size_t)(bn + row) * CDIM + c * 8;
        sslot[p] = s * 8;
    }

    const int lane = tid & 63, w = tid >> 6;
    const int wm = w >> 1, wn = w & 1;
    const int lrow = lane & 15, lhi = lane >> 4;

    f32x4 acc[2][2];
    #pragma unroll
    for (int mt = 0; mt < 2; ++mt)
        #pragma unroll
        for (int nt = 0; nt < 2; ++nt)
            acc[mt][nt] = (f32x4){0.f, 0.f, 0.f, 0.f};

    for (int k0 = 0; k0 < CDIM; k0 += 64) {
        #pragma unroll
        for (int p = 0; p < 2; ++p) {
            gload_lds16(asrc[p] + k0, sA + sslot[p]);
            gload_lds16(bsrc[p] + k0, sB + sslot[p]);
        }
        __syncthreads();
        #pragma unroll
        for (int ks = 0; ks < 2; ++ks) {
            half8 af[2], bf[2];
            #pragma unroll
            for (int mt = 0; mt < 2; ++mt) {
                int row = wm * 32 + mt * 16 + lrow;
                int sub = (ks * 4 + lhi) ^ (row & 7);
                af[mt] = *(const half8*)&sA[row * 64 + sub * 8];
            }
            #pragma unroll
            for (int nt = 0; nt < 2; ++nt) {
                int row = wn * 32 + nt * 16 + lrow;
                int sub = (ks * 4 + lhi) ^ (row & 7);
                bf[nt] = *(const half8*)&sB[row * 64 + sub * 8];
            }
            #pragma unroll
            for (int mt = 0; mt < 2; ++mt)
                #pragma unroll
                for (int nt = 0; nt < 2; ++nt)
                    acc[mt][nt] = __builtin_amdgcn_mfma_f32_16x16x32_f16(af[mt], bf[nt], acc[mt][nt], 0, 0, 0);
        }
        __syncthreads();
    }

    _Float16* Op = (wsel == 0) ? O0 : (wsel == 2) ? O2 : O4;
    #pragma unroll
    for (int mt = 0; mt < 2; ++mt) {
        #pragma unroll
        for (int nt = 0; nt < 2; ++nt) {
            int col = bn + wn * 32 + nt * 16 + lrow;
            #pragma unroll
            for (int r = 0; r < 4; ++r) {
                int m = bm + wm * 32 + mt * 16 + lhi * 4 + r;
                if (m < Mv) {
                    _Float16 val = (_Float16)acc[mt][nt][r];
                    if (wsel == 1) {
                        int bb = m / 77, j = m % 77;
                        O1[((size_t)bb * 640 + col) * 80 + j] = val;
                    } else if (wsel == 3) {
                        int bb = m >> 2, t = m & 3;
                        O3[((size_t)bb * 640 + col) * 4 + t] = val;
                    } else {
                        Op[(size_t)m * 640 + col] = val;
                    }
                }
            }
        }
    }
}

// ---------------------------------------------------------------- f16 MFMA GEMM (BK=64, swizzled LDS)
// C[M,640] = A[M,640] @ BT[640,640]^T.
// ACVT: A is f32, converted during reg-staging. else A is f16 via global_load_lds.
// EPI 0: f16 store. EPI 1: 0.5*(acc+bias)+resid, f32.
template<int EPI, bool ACVT>
__global__ __launch_bounds__(256)
void gemm_f16(const void* __restrict__ Ap, const _Float16* __restrict__ BT,
              const float* __restrict__ bias, const float* __restrict__ resid,
              void* __restrict__ Cp)
{
    __shared__ __align__(16) _Float16 sA[128 * 64];
    __shared__ __align__(16) _Float16 sB[128 * 64];

    const int tid = threadIdx.x;
    const int lane = tid & 63;
    const int w = tid >> 6, wm = w >> 1, wn = w & 1;
    const int lrow = lane & 15, lhi = lane >> 4;
    const int bm = blockIdx.x * 128, bn = blockIdx.y * 128;

    f32x4 acc[4][4];
    #pragma unroll
    for (int mt = 0; mt < 4; ++mt)
        #pragma unroll
        for (int nt = 0; nt < 4; ++nt)
            acc[mt][nt] = (f32x4){0.f, 0.f, 0.f, 0.f};

    // per-thread staging geometry (row advances by 32 per p; sub fixed)
    const int ssub = tid & 7;
    const int srow0 = tid >> 3;                       // 0..31
    const int dsub = ssub ^ (srow0 & 7);              // (p*32 doesn't change row&7)

    for (int k0 = 0; k0 < 640; k0 += 64) {
        if (ACVT) {
            const float* A = (const float*)Ap;
            #pragma unroll
            for (int p = 0; p < 4; ++p) {
                int row = p * 32 + srow0;
                const float* src = A + (size_t)(bm + row) * 640 + k0 + ssub * 8;
                float4 f0 = *(const float4*)(src);
                float4 f1 = *(const float4*)(src + 4);
                half8 h = {(_Float16)f0.x, (_Float16)f0.y, (_Float16)f0.z, (_Float16)f0.w,
                           (_Float16)f1.x, (_Float16)f1.y, (_Float16)f1.z, (_Float16)f1.w};
                *(half8*)&sA[row * 64 + dsub * 8] = h;
            }
        } else {
            const _Float16* A = (const _Float16*)Ap;
            #pragma unroll
            for (int p = 0; p < 4; ++p) {
                int s = p * 256 + tid;
                int row = s >> 3, sub = s & 7;
                int c = sub ^ (row & 7);
                gload_lds16(A + (size_t)(bm + row) * 640 + k0 + c * 8, sA + s * 8);
            }
        }
        #pragma unroll
        for (int p = 0; p < 4; ++p) {
            int s = p * 256 + tid;
            int row = s >> 3, sub = s & 7;
            int c = sub ^ (row & 7);
            gload_lds16(BT + (size_t)(bn + row) * 640 + k0 + c * 8, sB + s * 8);
        }
        __syncthreads();
        #pragma unroll
        for (int ks = 0; ks < 2; ++ks) {
            half8 af[4], bf[4];
            #pragma unroll
            for (int mt = 0; mt < 4; ++mt) {
                int row = wm * 64 + mt * 16 + lrow;
                int sub = (ks * 4 + lhi) ^ (row & 7);
                af[mt] = *(const half8*)&sA[row * 64 + sub * 8];
            }
            #pragma unroll
            for (int nt = 0; nt < 4; ++nt) {
                int row = wn * 64 + nt * 16 + lrow;
                int sub = (ks * 4 + lhi) ^ (row & 7);
                bf[nt] = *(const half8*)&sB[row * 64 + sub * 8];
            }
            #pragma unroll
            for (int mt = 0; mt < 4; ++mt)
                #pragma unroll
                for (int nt = 0; nt < 4; ++nt)
                    acc[mt][nt] = __builtin_amdgcn_mfma_f32_16x16x32_f16(af[mt], bf[nt], acc[mt][nt], 0, 0, 0);
        }
        __syncthreads();
    }

    #pragma unroll
    for (int mt = 0; mt < 4; ++mt) {
        #pragma unroll
        for (int nt = 0; nt < 4; ++nt) {
            int row0 = bm + wm * 64 + mt * 16 + lhi * 4;
            int col = bn + wn * 64 + nt * 16 + lrow;
            #pragma unroll
            for (int r = 0; r < 4; ++r) {
                float v = acc[mt][nt][r];
                if (EPI == 0) {
                    ((_Float16*)Cp)[(size_t)(row0 + r) * 640 + col] = (_Float16)v;
                } else {
                    float o = 0.5f * (v + bias[col]) + resid[(size_t)(row0 + r) * 640 + col];
                    ((float*)Cp)[(size_t)(row0 + r) * 640 + col] = o;
                }
            }
        }
    }
}

// ---------------------------------------------------------------- MFMA attention
// Block: 64 queries x one (b,h). 4 waves, 16 q-rows each.
// K-pack rows: 0..76 text, 77..79 zero, 80..83 ip, 84..87 ips, 88..95 zero.
// V^T comes pre-transposed from proj_gemm (vT, ipvT) -> no in-kernel transpose.
// Q A-frags read directly from global (no sQ). attnout aliases qh (in-place):
// each wave's q reads are consumed by QK MFMAs before its writes; regions disjoint.
__global__ __launch_bounds__(256, 3)
void attn_kernel(const _Float16* __restrict__ qh,
                 const _Float16* __restrict__ ktxt, const _Float16* __restrict__ vT,
                 const _Float16* __restrict__ ipk, const _Float16* __restrict__ ipvT,
                 const _Float16* __restrict__ ipsk, const int* __restrict__ mask,
                 _Float16* __restrict__ attnout)
{
    __shared__ __align__(16) _Float16 sK[96 * ASTR];
    __shared__ __align__(16) _Float16 sVT[80 * ASTR];  // [d][j]: j 0..76 text V, 80..83 ipV, rest 0
    __shared__ __align__(16) _Float16 sP[64 * ASTR];

    const int tile = blockIdx.x;
    const int bh = blockIdx.y;
    const int b = bh >> 3, h = bh & 7;
    const int tid = threadIdx.x;
    const float scale = 0.11180339887498948f;   // 1/sqrt(80)
    const half8 hz = {0, 0, 0, 0, 0, 0, 0, 0};

    // ---- stage K-pack
    for (int idx = tid; idx < 96 * 13; idx += 256) {
        int row = idx / 13, c8 = idx % 13;
        half8 v = hz;
        if (c8 < 10) {
            if (row < 77)                       v = *(const half8*)&ktxt[(size_t)(b * LTXT + row) * 640 + h * DH + c8 * 8];
            else if (row >= 80 && row < 84)     v = *(const half8*)&ipk [(size_t)(b * NTOK + row - 80) * 640 + h * DH + c8 * 8];
            else if (row >= 84 && row < 88)     v = *(const half8*)&ipsk[(size_t)(b * NTOK + row - 84) * 640 + h * DH + c8 * 8];
        }
        *(half8*)&sK[row * ASTR + c8 * 8] = v;
    }
    // ---- stage V^T (coalesced; cols 80..83 <- ipvT, 84.. zero)
    for (int idx = tid; idx < 80 * 13; idx += 256) {
        int row = idx / 13, c8 = idx % 13;
        size_t g = (size_t)b * 640 + h * DH + row;
        half8 v = hz;
        if (c8 < 10) {
            v = *(const half8*)&vT[g * 80 + c8 * 8];
            // j slots 77..79 are unwritten scratch (finite poison) but P there is 0
        } else if (c8 == 10) {
            half4 ip = *(const half4*)&ipvT[g * 4];
            v[0] = ip[0]; v[1] = ip[1]; v[2] = ip[2]; v[3] = ip[3];
        }
        *(half8*)&sVT[row * ASTR + c8 * 8] = v;
    }
    __syncthreads();

    // ---- per-wave compute
    const int lane = tid & 63;
    const int w = tid >> 6;
    const int rb = w * 16;
    const int lrow = lane & 15, lhi = lane >> 4;

    // Q A-frags direct from global (row = rb+lrow, cols lhi*8 + {0,32,64}; >=80 -> 0)
    const _Float16* qbase = qh + (size_t)(b * SS + tile * 64 + rb + lrow) * 640 + h * DH + lhi * 8;
    half8 a0 = *(const half8*)(qbase);
    half8 a1 = *(const half8*)(qbase + 32);
    half8 a2 = (lhi < 2) ? *(const half8*)(qbase + 64) : hz;

    f32x4 acc[6];
    #pragma unroll
    for (int nt = 0; nt < 6; ++nt) acc[nt] = (f32x4){0.f, 0.f, 0.f, 0.f};

    #pragma unroll
    for (int nt = 0; nt < 6; ++nt) {
        const _Float16* kb = &sK[(nt * 16 + lrow) * ASTR + lhi * 8];
        acc[nt] = __builtin_amdgcn_mfma_f32_16x16x32_f16(a0, *(const half8*)(kb),      acc[nt], 0, 0, 0);
        acc[nt] = __builtin_amdgcn_mfma_f32_16x16x32_f16(a1, *(const half8*)(kb + 32), acc[nt], 0, 0, 0);
        acc[nt] = __builtin_amdgcn_mfma_f32_16x16x32_f16(a2, *(const half8*)(kb + 64), acc[nt], 0, 0, 0);
    }

    #pragma unroll
    for (int nt = 0; nt < 6; ++nt) acc[nt] = acc[nt] * scale;

    const bool t4ok = (64 + lrow) < 77;
    #pragma unroll
    for (int r = 0; r < 4; ++r) {
        // text softmax over cols 0..76
        float v4 = t4ok ? acc[4][r] : -1e30f;
        float m = fmaxf(fmaxf(acc[0][r], acc[1][r]), fmaxf(acc[2][r], acc[3][r]));
        m = fmaxf(m, v4);
        m = fmaxf(m, __shfl_xor(m, 1));
        m = fmaxf(m, __shfl_xor(m, 2));
        m = fmaxf(m, __shfl_xor(m, 4));
        m = fmaxf(m, __shfl_xor(m, 8));
        float e0 = __expf(acc[0][r] - m), e1 = __expf(acc[1][r] - m);
        float e2 = __expf(acc[2][r] - m), e3 = __expf(acc[3][r] - m);
        float e4 = t4ok ? __expf(acc[4][r] - m) : 0.f;
        float sm = e0 + e1 + e2 + e3 + e4;
        sm += __shfl_xor(sm, 1); sm += __shfl_xor(sm, 2);
        sm += __shfl_xor(sm, 4); sm += __shfl_xor(sm, 8);
        float inv = 1.f / sm;
        acc[0][r] = e0 * inv; acc[1][r] = e1 * inv; acc[2][r] = e2 * inv;
        acc[3][r] = e3 * inv; acc[4][r] = e4 * inv;

        // ip/ips softmax: cols 80..83 (lanes 0..3) and 84..87 (lanes 4..7)
        float s5 = acc[5][r];
        float m5 = fmaxf(s5, __shfl_xor(s5, 1));
        m5 = fmaxf(m5, __shfl_xor(m5, 2));
        float e5 = __expf(s5 - m5);
        float sm5 = e5 + __shfl_xor(e5, 1);
        sm5 += __shfl_xor(sm5, 2);
        float p5 = e5 / sm5;
        float po = __shfl_xor(p5, 4);
        int gq = tile * 64 + rb + lhi * 4 + r;
        float fac = (mask[gq] != 0) ? 0.01f : 1.0f;
        float pc = fmaxf(p5, po) * fac;
        acc[5][r] = (lrow < 4) ? pc : 0.f;
    }

    // write P (wave-local rows: rb..rb+15, cols 0..95)
    #pragma unroll
    for (int nt = 0; nt < 6; ++nt)
        #pragma unroll
        for (int r = 0; r < 4; ++r)
            sP[(rb + lhi * 4 + r) * ASTR + nt * 16 + lrow] = (_Float16)acc[nt][r];

    // PV (wave reads only its own P rows; sVT staged before barrier)
    f32x4 o[5];
    #pragma unroll
    for (int nt = 0; nt < 5; ++nt) o[nt] = (f32x4){0.f, 0.f, 0.f, 0.f};
    {
        const _Float16* pbase = &sP[(rb + lrow) * ASTR + lhi * 8];
        half8 p0 = *(const half8*)(pbase);
        half8 p1 = *(const half8*)(pbase + 32);
        half8 p2 = *(const half8*)(pbase + 64);
        #pragma unroll
        for (int nt = 0; nt < 5; ++nt) {
            const _Float16* vb = &sVT[(nt * 16 + lrow) * ASTR + lhi * 8];
            o[nt] = __builtin_amdgcn_mfma_f32_16x16x32_f16(p0, *(const half8*)(vb),      o[nt], 0, 0, 0);
            o[nt] = __builtin_amdgcn_mfma_f32_16x16x32_f16(p1, *(const half8*)(vb + 32), o[nt], 0, 0, 0);
            o[nt] = __builtin_amdgcn_mfma_f32_16x16x32_f16(p2, *(const half8*)(vb + 64), o[nt], 0, 0, 0);
        }
    }

    #pragma unroll
    for (int nt = 0; nt < 5; ++nt)
        #pragma unroll
        for (int r = 0; r < 4; ++r)
            attnout[(size_t)(b * SS + tile * 64 + rb + lhi * 4 + r) * 640 + h * DH + nt * 16 + lrow] =
                (_Float16)o[nt][r];
}

// ---------------------------------------------------------------- launch
extern "C" void kernel_launch(void* const* d_in, const int* in_sizes, int n_in,
                              void* d_out, int out_size, void* d_ws, size_t ws_size,
                              hipStream_t stream) {
    const float* hidden = (const float*)d_in[0];
    const float* ehs    = (const float*)d_in[1];
    const int*   mask   = (const int*)d_in[2];
    const float* Wq     = (const float*)d_in[3];
    const float* Wk     = (const float*)d_in[4];
    const float* Wv     = (const float*)d_in[5];
    const float* Wkip   = (const float*)d_in[6];
    const float* Wvip   = (const float*)d_in[7];
    const float* Wksip  = (const float*)d_in[8];
    const float* Wo     = (const float*)d_in[9];
    const float* bo     = (const float*)d_in[10];

    char* ws = (char*)d_ws;
    _Float16* qhA    = (_Float16*)(ws);                      // 41,943,040 B: q -> attn out (in-place)
    _Float16* BqT    = (_Float16*)(ws + 41943040);           // 819,200 B
    _Float16* BoT    = (_Float16*)(ws + 42762240);           // 819,200 B
    _Float16* ktxt   = (_Float16*)(ws + 43581440);           // 788,480 B
    _Float16* vT     = (_Float16*)(ws + 44369920);           // 819,200 B  [b*640+d][80]
    _Float16* ipk    = (_Float16*)(ws + 45189120);           // 40,960 B
    _Float16* ipvT   = (_Float16*)(ws + 45230080);           // 40,960 B  [b*640+d][4]
    _Float16* ipsk   = (_Float16*)(ws + 45271040);           // 40,960 B
    _Float16* ehs16  = (_Float16*)(ws + 45312000);           // 1,044,480 B
    _Float16* WkT    = (_Float16*)(ws + 46356480);           // 983,040 B each
    _Float16* WvT    = (_Float16*)(ws + 47339520);
    _Float16* WkipT  = (_Float16*)(ws + 48322560);
    _Float16* WvipT  = (_Float16*)(ws + 49305600);
    _Float16* WksipT = (_Float16*)(ws + 50288640);           // ends 51,271,680 B

    convert_a<<<255, 256, 0, stream>>>(ehs, ehs16, 65280);
    convert_bt2<<<dim3(10, 10, 2), 256, 0, stream>>>(Wq, Wo, BqT, BoT, 640);
    convert_bt5<<<dim3(10, 12, 5), 256, 0, stream>>>(Wk, Wv, Wkip, Wvip, Wksip,
                                                     WkT, WvT, WkipT, WvipT, WksipT);
    proj_gemm<<<230, 256, 0, stream>>>(ehs16, WkT, WvT, WkipT, WvipT, WksipT,
                                       ktxt, vT, ipk, ipvT, ipsk);
    gemm_f16<0, true><<<dim3(256, 5), 256, 0, stream>>>(hidden, BqT, nullptr, nullptr, qhA);
    attn_kernel<<<dim3(64, 64), 256, 0, stream>>>(qhA, ktxt, vT, ipk, ipvT, ipsk, mask, qhA);
    gemm_f16<1, false><<<dim3(256, 5), 256, 0, stream>>>(qhA, BoT, bo, hidden, d_out);
}

// Round 6
// 196.237 us; speedup vs baseline: 3.4140x; 1.0726x over previous
//
#include <hip/hip_runtime.h>
#include <hip/hip_bf16.h>
#include <hip/hip_fp16.h>

#define BB 8
#define SS 4096
#define CC 640
#define CDIM 768
#define LTXT 77
#define NTOK 4
#define DH 80
#define ASTR 104   // padded LDS row stride (f16) for attention tiles

typedef __attribute__((ext_vector_type(8))) _Float16 half8;
typedef __attribute__((ext_vector_type(4))) _Float16 half4;
typedef __attribute__((ext_vector_type(4))) float f32x4;

__device__ inline void gload_lds16(const void* g, void* l) {
    __builtin_amdgcn_global_load_lds((__attribute__((address_space(1))) void*)g,
                                     (__attribute__((address_space(3))) void*)l, 16, 0, 0);
}

// ---------------------------------------------------------------- converts
__global__ __launch_bounds__(256)
void convert_a(const float* __restrict__ in, _Float16* __restrict__ out, int n8) {
    int i = blockIdx.x * 256 + threadIdx.x;
    if (i < n8) {
        const float4* p = (const float4*)(in + (size_t)i * 8);
        float4 a = p[0], b = p[1];
        half8 h = {(_Float16)a.x, (_Float16)a.y, (_Float16)a.z, (_Float16)a.w,
                   (_Float16)b.x, (_Float16)b.y, (_Float16)b.z, (_Float16)b.w};
        *(half8*)(out + (size_t)i * 8) = h;
    }
}

// W[K][640] f32 -> T[n][k] f16 (transposed). z selects which of two weights.
__global__ __launch_bounds__(256)
void convert_bt2(const float* __restrict__ W0, const float* __restrict__ W1,
                 _Float16* __restrict__ T0, _Float16* __restrict__ T1, int K) {
    __shared__ float t[64][65];
    const float* W = blockIdx.z ? W1 : W0;
    _Float16* T = blockIdx.z ? T1 : T0;
    int n0 = blockIdx.x * 64, k0 = blockIdx.y * 64;
    for (int idx = threadIdx.x; idx < 64 * 64; idx += 256) {
        int kk = idx >> 6, nn = idx & 63;
        t[kk][nn] = W[(size_t)(k0 + kk) * 640 + n0 + nn];
    }
    __syncthreads();
    for (int idx = threadIdx.x; idx < 64 * 64; idx += 256) {
        int nn = idx >> 6, kk = idx & 63;
        T[(size_t)(n0 + nn) * K + k0 + kk] = (_Float16)t[kk][nn];
    }
}

// 5 projection weights [768][640] f32 -> [640][768] f16, z selects weight
__global__ __launch_bounds__(256)
void convert_bt5(const float* __restrict__ W0, const float* __restrict__ W1,
                 const float* __restrict__ W2, const float* __restrict__ W3,
                 const float* __restrict__ W4,
                 _Float16* __restrict__ T0, _Float16* __restrict__ T1,
                 _Float16* __restrict__ T2, _Float16* __restrict__ T3,
                 _Float16* __restrict__ T4) {
    __shared__ float t[64][65];
    int z = blockIdx.z;
    const float* W = (z == 0) ? W0 : (z == 1) ? W1 : (z == 2) ? W2 : (z == 3) ? W3 : W4;
    _Float16* T = (z == 0) ? T0 : (z == 1) ? T1 : (z == 2) ? T2 : (z == 3) ? T3 : T4;
    int n0 = blockIdx.x * 64, k0 = blockIdx.y * 64;
    for (int idx = threadIdx.x; idx < 64 * 64; idx += 256) {
        int kk = idx >> 6, nn = idx & 63;
        t[kk][nn] = W[(size_t)(k0 + kk) * 640 + n0 + nn];
    }
    __syncthreads();
    for (int idx = threadIdx.x; idx < 64 * 64; idx += 256) {
        int nn = idx >> 6, kk = idx & 63;
        T[(size_t)(n0 + nn) * CDIM + k0 + kk] = (_Float16)t[kk][nn];
    }
}

// ---------------------------------------------------------------- projection MFMA GEMM
// Virtual jobs: 0..199 text (wsel 0,1: Wk,Wv; M=616), 200..229 ip (wsel 2,3,4; M=32).
// wsel==1 (V) writes TRANSPOSED: vT[(b*640+col)*80 + j]; wsel==3 (ipV): ipvT[(b*640+col)*4 + t]
__global__ __launch_bounds__(256)
void proj_gemm(const _Float16* __restrict__ A16,
               const _Float16* __restrict__ WT0, const _Float16* __restrict__ WT1,
               const _Float16* __restrict__ WT2, const _Float16* __restrict__ WT3,
               const _Float16* __restrict__ WT4,
               _Float16* __restrict__ O0, _Float16* __restrict__ O1,
               _Float16* __restrict__ O2, _Float16* __restrict__ O3,
               _Float16* __restrict__ O4)
{
    __shared__ __align__(16) _Float16 sA[64 * 64];
    __shared__ __align__(16) _Float16 sB[64 * 64];
    const int tid = threadIdx.x;
    const int job = blockIdx.x;
    int wsel, mtile, ntile;
    if (job < 200) { wsel = job / 100; mtile = (job % 100) / 10; ntile = job % 10; }
    else { int j = job - 200; wsel = 2 + j / 10; mtile = 0; ntile = j % 10; }
    const _Float16* WT = (wsel == 0) ? WT0 : (wsel == 1) ? WT1 : (wsel == 2) ? WT2 : (wsel == 3) ? WT3 : WT4;
    const int Mv = (wsel < 2) ? 616 : 32;
    const int bm = mtile * 64, bn = ntile * 64;

    const _Float16* asrc[2];
    const _Float16* bsrc[2];
    int sslot[2];
    #pragma unroll
    for (int p = 0; p < 2; ++p) {
        int s = p * 256 + tid;
        int row = s >> 3, sub = s & 7;
        int c = sub ^ (row & 7);
        int m = bm + row; if (m > Mv - 1) m = Mv - 1;
        int srcrow;
        if (wsel < 2) srcrow = (m / 77) * 85 + (m % 77);
        else { int b2 = m >> 2, t2 = m & 3; srcrow = b2 * 85 + ((wsel == 4) ? 81 : 77) + t2; }
        asrc[p] = A16 + (size_t)srcrow * CDIM + c * 8;
        bsrc[p] = WT + (size_t)(bn + row) * CDIM + c * 8;
        sslot[p] = s * 8;
    }

    const int lane = tid & 63, w = tid >> 6;
    const int wm = w >> 1, wn = w & 1;
    const int lrow = lane & 15, lhi = lane >> 4;

    f32x4 acc[2][2];
    #pragma unroll
    for (int mt = 0; mt < 2; ++mt)
        #pragma unroll
        for (int nt = 0; nt < 2; ++nt)
            acc[mt][nt] = (f32x4){0.f, 0.f, 0.f, 0.f};

    for (int k0 = 0; k0 < CDIM; k0 += 64) {
        #pragma unroll
        for (int p = 0; p < 2; ++p) {
            gload_lds16(asrc[p] + k0, sA + sslot[p]);
            gload_lds16(bsrc[p] + k0, sB + sslot[p]);
        }
        __syncthreads();
        #pragma unroll
        for (int ks = 0; ks < 2; ++ks) {
            half8 af[2], bf[2];
            #pragma unroll
            for (int mt = 0; mt < 2; ++mt) {
                int row = wm * 32 + mt * 16 + lrow;
                int sub = (ks * 4 + lhi) ^ (row & 7);
                af[mt] = *(const half8*)&sA[row * 64 + sub * 8];
            }
            #pragma unroll
            for (int nt = 0; nt < 2; ++nt) {
                int row = wn * 32 + nt * 16 + lrow;
                int sub = (ks * 4 + lhi) ^ (row & 7);
                bf[nt] = *(const half8*)&sB[row * 64 + sub * 8];
            }
            #pragma unroll
            for (int mt = 0; mt < 2; ++mt)
                #pragma unroll
                for (int nt = 0; nt < 2; ++nt)
                    acc[mt][nt] = __builtin_amdgcn_mfma_f32_16x16x32_f16(af[mt], bf[nt], acc[mt][nt], 0, 0, 0);
        }
        __syncthreads();
    }

    _Float16* Op = (wsel == 0) ? O0 : (wsel == 2) ? O2 : O4;
    #pragma unroll
    for (int mt = 0; mt < 2; ++mt) {
        #pragma unroll
        for (int nt = 0; nt < 2; ++nt) {
            int col = bn + wn * 32 + nt * 16 + lrow;
            #pragma unroll
            for (int r = 0; r < 4; ++r) {
                int m = bm + wm * 32 + mt * 16 + lhi * 4 + r;
                if (m < Mv) {
                    _Float16 val = (_Float16)acc[mt][nt][r];
                    if (wsel == 1) {
                        int bb = m / 77, j = m % 77;
                        O1[((size_t)bb * 640 + col) * 80 + j] = val;
                    } else if (wsel == 3) {
                        int bb = m >> 2, t = m & 3;
                        O3[((size_t)bb * 640 + col) * 4 + t] = val;
                    } else {
                        Op[(size_t)m * 640 + col] = val;
                    }
                }
            }
        }
    }
}

// ---------------------------------------------------------------- f16 MFMA GEMM (BK=64, swizzled LDS)
// C[M,640] = A[M,640] @ BT[640,640]^T. 1D grid 1280, XCD-swizzled, n-inner.
// ACVT: A is f32, pipelined reg-staging (issue next tile's loads under MFMA).
// EPI 0: f16 store. EPI 1: 0.5*(acc+bias)+resid, f32.
template<int EPI, bool ACVT>
__global__ __launch_bounds__(256)
void gemm_f16(const void* __restrict__ Ap, const _Float16* __restrict__ BT,
              const float* __restrict__ bias, const float* __restrict__ resid,
              void* __restrict__ Cp)
{
    __shared__ __align__(16) _Float16 sA[128 * 64];
    __shared__ __align__(16) _Float16 sB[128 * 64];

    const int tid = threadIdx.x;
    const int lane = tid & 63;
    const int w = tid >> 6, wm = w >> 1, wn = w & 1;
    const int lrow = lane & 15, lhi = lane >> 4;

    // XCD-bijective swizzle (1280 = 8 * 160), n-inner so A-panel sharers are adjacent
    const int orig = blockIdx.x;
    const int wgid = (orig & 7) * 160 + (orig >> 3);
    const int bm = (wgid / 5) * 128, bn = (wgid % 5) * 128;

    f32x4 acc[4][4];
    #pragma unroll
    for (int mt = 0; mt < 4; ++mt)
        #pragma unroll
        for (int nt = 0; nt < 4; ++nt)
            acc[mt][nt] = (f32x4){0.f, 0.f, 0.f, 0.f};

    // reg-staging geometry (ACVT): row = p*32 + srow0, col chunk ssub
    const int ssub = tid & 7;
    const int srow0 = tid >> 3;
    const int dsub = ssub ^ (srow0 & 7);

    float4 f0[4], f1[4];
    if (ACVT) {
        const float* A = (const float*)Ap;
        #pragma unroll
        for (int p = 0; p < 4; ++p) {
            const float* src = A + (size_t)(bm + p * 32 + srow0) * 640 + ssub * 8;
            f0[p] = *(const float4*)(src);
            f1[p] = *(const float4*)(src + 4);
        }
    }

    for (int t = 0; t < 10; ++t) {
        const int k0 = t * 64;
        if (ACVT) {
            #pragma unroll
            for (int p = 0; p < 4; ++p) {
                int row = p * 32 + srow0;
                half8 h = {(_Float16)f0[p].x, (_Float16)f0[p].y, (_Float16)f0[p].z, (_Float16)f0[p].w,
                           (_Float16)f1[p].x, (_Float16)f1[p].y, (_Float16)f1[p].z, (_Float16)f1[p].w};
                *(half8*)&sA[row * 64 + dsub * 8] = h;
            }
        } else {
            const _Float16* A = (const _Float16*)Ap;
            #pragma unroll
            for (int p = 0; p < 4; ++p) {
                int s = p * 256 + tid;
                int row = s >> 3, sub = s & 7;
                int c = sub ^ (row & 7);
                gload_lds16(A + (size_t)(bm + row) * 640 + k0 + c * 8, sA + s * 8);
            }
        }
        #pragma unroll
        for (int p = 0; p < 4; ++p) {
            int s = p * 256 + tid;
            int row = s >> 3, sub = s & 7;
            int c = sub ^ (row & 7);
            gload_lds16(BT + (size_t)(bn + row) * 640 + k0 + c * 8, sB + s * 8);
        }
        __syncthreads();

        // issue NEXT tile's f32 loads now — latency hides under the MFMA phase
        if (ACVT && t < 9) {
            const float* A = (const float*)Ap;
            #pragma unroll
            for (int p = 0; p < 4; ++p) {
                const float* src = A + (size_t)(bm + p * 32 + srow0) * 640 + (k0 + 64) + ssub * 8;
                f0[p] = *(const float4*)(src);
                f1[p] = *(const float4*)(src + 4);
            }
        }

        #pragma unroll
        for (int ks = 0; ks < 2; ++ks) {
            half8 af[4], bf[4];
            #pragma unroll
            for (int mt = 0; mt < 4; ++mt) {
                int row = wm * 64 + mt * 16 + lrow;
                int sub = (ks * 4 + lhi) ^ (row & 7);
                af[mt] = *(const half8*)&sA[row * 64 + sub * 8];
            }
            #pragma unroll
            for (int nt = 0; nt < 4; ++nt) {
                int row = wn * 64 + nt * 16 + lrow;
                int sub = (ks * 4 + lhi) ^ (row & 7);
                bf[nt] = *(const half8*)&sB[row * 64 + sub * 8];
            }
            #pragma unroll
            for (int mt = 0; mt < 4; ++mt)
                #pragma unroll
                for (int nt = 0; nt < 4; ++nt)
                    acc[mt][nt] = __builtin_amdgcn_mfma_f32_16x16x32_f16(af[mt], bf[nt], acc[mt][nt], 0, 0, 0);
        }
        __syncthreads();
    }

    #pragma unroll
    for (int mt = 0; mt < 4; ++mt) {
        #pragma unroll
        for (int nt = 0; nt < 4; ++nt) {
            int row0 = bm + wm * 64 + mt * 16 + lhi * 4;
            int col = bn + wn * 64 + nt * 16 + lrow;
            #pragma unroll
            for (int r = 0; r < 4; ++r) {
                float v = acc[mt][nt][r];
                if (EPI == 0) {
                    ((_Float16*)Cp)[(size_t)(row0 + r) * 640 + col] = (_Float16)v;
                } else {
                    float o = 0.5f * (v + bias[col]) + resid[(size_t)(row0 + r) * 640 + col];
                    ((float*)Cp)[(size_t)(row0 + r) * 640 + col] = o;
                }
            }
        }
    }
}

// ---------------------------------------------------------------- MFMA attention
// Block: 64 queries x one (b,h). 4 waves, 16 q-rows each.
// K-pack rows: 0..76 text, 77..79 zero, 80..83 ip, 84..87 ips, 88..95 zero.
// V^T pre-transposed by proj_gemm. Q A-frags direct from global. attnout aliases qh.
__global__ __launch_bounds__(256, 3)
void attn_kernel(const _Float16* __restrict__ qh,
                 const _Float16* __restrict__ ktxt, const _Float16* __restrict__ vT,
                 const _Float16* __restrict__ ipk, const _Float16* __restrict__ ipvT,
                 const _Float16* __restrict__ ipsk, const int* __restrict__ mask,
                 _Float16* __restrict__ attnout)
{
    __shared__ __align__(16) _Float16 sK[96 * ASTR];
    __shared__ __align__(16) _Float16 sVT[80 * ASTR];
    __shared__ __align__(16) _Float16 sP[64 * ASTR];

    const int tile = blockIdx.x;
    const int bh = blockIdx.y;
    const int b = bh >> 3, h = bh & 7;
    const int tid = threadIdx.x;
    const float scale = 0.11180339887498948f;   // 1/sqrt(80)
    const half8 hz = {0, 0, 0, 0, 0, 0, 0, 0};

    for (int idx = tid; idx < 96 * 13; idx += 256) {
        int row = idx / 13, c8 = idx % 13;
        half8 v = hz;
        if (c8 < 10) {
            if (row < 77)                       v = *(const half8*)&ktxt[(size_t)(b * LTXT + row) * 640 + h * DH + c8 * 8];
            else if (row >= 80 && row < 84)     v = *(const half8*)&ipk [(size_t)(b * NTOK + row - 80) * 640 + h * DH + c8 * 8];
            else if (row >= 84 && row < 88)     v = *(const half8*)&ipsk[(size_t)(b * NTOK + row - 84) * 640 + h * DH + c8 * 8];
        }
        *(half8*)&sK[row * ASTR + c8 * 8] = v;
    }
    for (int idx = tid; idx < 80 * 13; idx += 256) {
        int row = idx / 13, c8 = idx % 13;
        size_t g = (size_t)b * 640 + h * DH + row;
        half8 v = hz;
        if (c8 < 10) {
            v = *(const half8*)&vT[g * 80 + c8 * 8];
        } else if (c8 == 10) {
            half4 ip = *(const half4*)&ipvT[g * 4];
            v[0] = ip[0]; v[1] = ip[1]; v[2] = ip[2]; v[3] = ip[3];
        }
        *(half8*)&sVT[row * ASTR + c8 * 8] = v;
    }
    __syncthreads();

    const int lane = tid & 63;
    const int w = tid >> 6;
    const int rb = w * 16;
    const int lrow = lane & 15, lhi = lane >> 4;

    const _Float16* qbase = qh + (size_t)(b * SS + tile * 64 + rb + lrow) * 640 + h * DH + lhi * 8;
    half8 a0 = *(const half8*)(qbase);
    half8 a1 = *(const half8*)(qbase + 32);
    half8 a2 = (lhi < 2) ? *(const half8*)(qbase + 64) : hz;

    f32x4 acc[6];
    #pragma unroll
    for (int nt = 0; nt < 6; ++nt) acc[nt] = (f32x4){0.f, 0.f, 0.f, 0.f};

    #pragma unroll
    for (int nt = 0; nt < 6; ++nt) {
        const _Float16* kb = &sK[(nt * 16 + lrow) * ASTR + lhi * 8];
        acc[nt] = __builtin_amdgcn_mfma_f32_16x16x32_f16(a0, *(const half8*)(kb),      acc[nt], 0, 0, 0);
        acc[nt] = __builtin_amdgcn_mfma_f32_16x16x32_f16(a1, *(const half8*)(kb + 32), acc[nt], 0, 0, 0);
        acc[nt] = __builtin_amdgcn_mfma_f32_16x16x32_f16(a2, *(const half8*)(kb + 64), acc[nt], 0, 0, 0);
    }

    #pragma unroll
    for (int nt = 0; nt < 6; ++nt) acc[nt] = acc[nt] * scale;

    const bool t4ok = (64 + lrow) < 77;
    #pragma unroll
    for (int r = 0; r < 4; ++r) {
        float v4 = t4ok ? acc[4][r] : -1e30f;
        float m = fmaxf(fmaxf(acc[0][r], acc[1][r]), fmaxf(acc[2][r], acc[3][r]));
        m = fmaxf(m, v4);
        m = fmaxf(m, __shfl_xor(m, 1));
        m = fmaxf(m, __shfl_xor(m, 2));
        m = fmaxf(m, __shfl_xor(m, 4));
        m = fmaxf(m, __shfl_xor(m, 8));
        float e0 = __expf(acc[0][r] - m), e1 = __expf(acc[1][r] - m);
        float e2 = __expf(acc[2][r] - m), e3 = __expf(acc[3][r] - m);
        float e4 = t4ok ? __expf(acc[4][r] - m) : 0.f;
        float sm = e0 + e1 + e2 + e3 + e4;
        sm += __shfl_xor(sm, 1); sm += __shfl_xor(sm, 2);
        sm += __shfl_xor(sm, 4); sm += __shfl_xor(sm, 8);
        float inv = 1.f / sm;
        acc[0][r] = e0 * inv; acc[1][r] = e1 * inv; acc[2][r] = e2 * inv;
        acc[3][r] = e3 * inv; acc[4][r] = e4 * inv;

        float s5 = acc[5][r];
        float m5 = fmaxf(s5, __shfl_xor(s5, 1));
        m5 = fmaxf(m5, __shfl_xor(m5, 2));
        float e5 = __expf(s5 - m5);
        float sm5 = e5 + __shfl_xor(e5, 1);
        sm5 += __shfl_xor(sm5, 2);
        float p5 = e5 / sm5;
        float po = __shfl_xor(p5, 4);
        int gq = tile * 64 + rb + lhi * 4 + r;
        float fac = (mask[gq] != 0) ? 0.01f : 1.0f;
        float pc = fmaxf(p5, po) * fac;
        acc[5][r] = (lrow < 4) ? pc : 0.f;
    }

    #pragma unroll
    for (int nt = 0; nt < 6; ++nt)
        #pragma unroll
        for (int r = 0; r < 4; ++r)
            sP[(rb + lhi * 4 + r) * ASTR + nt * 16 + lrow] = (_Float16)acc[nt][r];

    f32x4 o[5];
    #pragma unroll
    for (int nt = 0; nt < 5; ++nt) o[nt] = (f32x4){0.f, 0.f, 0.f, 0.f};
    {
        const _Float16* pbase = &sP[(rb + lrow) * ASTR + lhi * 8];
        half8 p0 = *(const half8*)(pbase);
        half8 p1 = *(const half8*)(pbase + 32);
        half8 p2 = *(const half8*)(pbase + 64);
        #pragma unroll
        for (int nt = 0; nt < 5; ++nt) {
            const _Float16* vb = &sVT[(nt * 16 + lrow) * ASTR + lhi * 8];
            o[nt] = __builtin_amdgcn_mfma_f32_16x16x32_f16(p0, *(const half8*)(vb),      o[nt], 0, 0, 0);
            o[nt] = __builtin_amdgcn_mfma_f32_16x16x32_f16(p1, *(const half8*)(vb + 32), o[nt], 0, 0, 0);
            o[nt] = __builtin_amdgcn_mfma_f32_16x16x32_f16(p2, *(const half8*)(vb + 64), o[nt], 0, 0, 0);
        }
    }

    #pragma unroll
    for (int nt = 0; nt < 5; ++nt)
        #pragma unroll
        for (int r = 0; r < 4; ++r)
            attnout[(size_t)(b * SS + tile * 64 + rb + lhi * 4 + r) * 640 + h * DH + nt * 16 + lrow] =
                (_Float16)o[nt][r];
}

// ---------------------------------------------------------------- launch
extern "C" void kernel_launch(void* const* d_in, const int* in_sizes, int n_in,
                              void* d_out, int out_size, void* d_ws, size_t ws_size,
                              hipStream_t stream) {
    const float* hidden = (const float*)d_in[0];
    const float* ehs    = (const float*)d_in[1];
    const int*   mask   = (const int*)d_in[2];
    const float* Wq     = (const float*)d_in[3];
    const float* Wk     = (const float*)d_in[4];
    const float* Wv     = (const float*)d_in[5];
    const float* Wkip   = (const float*)d_in[6];
    const float* Wvip   = (const float*)d_in[7];
    const float* Wksip  = (const float*)d_in[8];
    const float* Wo     = (const float*)d_in[9];
    const float* bo     = (const float*)d_in[10];

    char* ws = (char*)d_ws;
    _Float16* qhA    = (_Float16*)(ws);                      // 41,943,040 B: q -> attn out (in-place)
    _Float16* BqT    = (_Float16*)(ws + 41943040);           // 819,200 B
    _Float16* BoT    = (_Float16*)(ws + 42762240);           // 819,200 B
    _Float16* ktxt   = (_Float16*)(ws + 43581440);           // 788,480 B
    _Float16* vT     = (_Float16*)(ws + 44369920);           // 819,200 B  [b*640+d][80]
    _Float16* ipk    = (_Float16*)(ws + 45189120);           // 40,960 B
    _Float16* ipvT   = (_Float16*)(ws + 45230080);           // 40,960 B  [b*640+d][4]
    _Float16* ipsk   = (_Float16*)(ws + 45271040);           // 40,960 B
    _Float16* ehs16  = (_Float16*)(ws + 45312000);           // 1,044,480 B
    _Float16* WkT    = (_Float16*)(ws + 46356480);           // 983,040 B each
    _Float16* WvT    = (_Float16*)(ws + 47339520);
    _Float16* WkipT  = (_Float16*)(ws + 48322560);
    _Float16* WvipT  = (_Float16*)(ws + 49305600);
    _Float16* WksipT = (_Float16*)(ws + 50288640);           // ends 51,271,680 B

    convert_a<<<255, 256, 0, stream>>>(ehs, ehs16, 65280);
    convert_bt2<<<dim3(10, 10, 2), 256, 0, stream>>>(Wq, Wo, BqT, BoT, 640);
    convert_bt5<<<dim3(10, 12, 5), 256, 0, stream>>>(Wk, Wv, Wkip, Wvip, Wksip,
                                                     WkT, WvT, WkipT, WvipT, WksipT);
    proj_gemm<<<230, 256, 0, stream>>>(ehs16, WkT, WvT, WkipT, WvipT, WksipT,
                                       ktxt, vT, ipk, ipvT, ipsk);
    gemm_f16<0, true><<<1280, 256, 0, stream>>>(hidden, BqT, nullptr, nullptr, qhA);
    attn_kernel<<<dim3(64, 64), 256, 0, stream>>>(qhA, ktxt, vT, ipk, ipvT, ipsk, mask, qhA);
    gemm_f16<1, false><<<1280, 256, 0, stream>>>(qhA, BoT, bo, hidden, d_out);
}